// Round 1
// 1308.792 us; speedup vs baseline: 3.3486x; 3.3486x over previous
//
#include <hip/hip_runtime.h>
#include <hip/hip_bf16.h>
#include <stdint.h>

#define B_    64
#define D_    768
#define NVOC  100000
#define VK    512
#define KH    256

__device__ __forceinline__ float b2f_raw(unsigned short u) {
    return __uint_as_float(((unsigned int)u) << 16);
}
// dtype-generic input load: isbf=1 -> bf16, else f32
__device__ __forceinline__ float ldin(const void* p, size_t i, int isbf) {
    return isbf ? b2f_raw(((const unsigned short*)p)[i]) : ((const float*)p)[i];
}
__device__ __forceinline__ float4 ldin4(const void* p, size_t i, int isbf) {
    if (isbf) {
        ushort4 r = *(const ushort4*)((const unsigned short*)p + i);
        return make_float4(b2f_raw(r.x), b2f_raw(r.y), b2f_raw(r.z), b2f_raw(r.w));
    }
    return *(const float4*)((const float*)p + i);
}
// monotonic float->uint map (order-preserving)
__device__ __forceinline__ uint32_t fmono(float x) {
    uint32_t u = __float_as_uint(x);
    return u ^ (uint32_t)((((int32_t)u) >> 31) | 0x80000000u);
}

__device__ __forceinline__ float block_reduce_sum_256(float v, float* red) {
    int tid = threadIdx.x;
    red[tid] = v; __syncthreads();
    #pragma unroll
    for (int s = 128; s > 0; s >>= 1) {
        if (tid < s) red[tid] += red[tid + s];
        __syncthreads();
    }
    float r = red[0]; __syncthreads();
    return r;
}

// ---------------- dtype detector: f32 N(0,1) data vs bf16 data misread as f32 --------
__global__ void detect_kernel(const void* vocab, int* flag) {
    if (threadIdx.x == 0 && blockIdx.x == 0) {
        const float* vf = (const float*)vocab;
        int sane = 0;
        for (int i = 0; i < 256; i++) {
            float a = fabsf(vf[i]);
            if (a > 1e-4f && a < 64.0f) sane++;
        }
        *flag = (sane >= 200) ? 0 : 1;   // 0 = f32 inputs, 1 = bf16 inputs
    }
}

// ---------------- prep: pools into concat + per-embedding inverse norms ----------------
// invemb layout: [b][25]; i=0..8 pos, 9..16 neg, 17..23 neut, 24 assas
// concat layout: [b][3072] = [neg_pool | assas_raw | neut_pool | pos_pool]
__global__ __launch_bounds__(256) void prep_kernel(
    const void* __restrict__ pos, const void* __restrict__ neg,
    const void* __restrict__ neut, const void* __restrict__ assas,
    float* __restrict__ concat, float* __restrict__ invemb,
    const int* __restrict__ dflag) {
    __shared__ float red[256];
    int isbf = *dflag;
    int b = blockIdx.x, tid = threadIdx.x;
    int d = tid * 3;
    const void* srcs[3] = {pos, neg, neut};
    const int cnts[3]  = {9, 8, 7};
    const int ieoff[3] = {0, 9, 17};
    const int coff[3]  = {2304, 0, 1536};
    for (int g = 0; g < 3; g++) {
        float m0 = 0.f, m1 = 0.f, m2 = 0.f;
        int cnt = cnts[g];
        for (int m = 0; m < cnt; m++) {
            size_t base = ((size_t)b * cnt + m) * D_ + d;
            float x0 = ldin(srcs[g], base + 0, isbf);
            float x1 = ldin(srcs[g], base + 1, isbf);
            float x2 = ldin(srcs[g], base + 2, isbf);
            float S = block_reduce_sum_256(x0 * x0 + x1 * x1 + x2 * x2, red);
            if (tid == 0)
                invemb[b * 25 + ieoff[g] + m] = 1.0f / fmaxf(sqrtf(S), 1e-12f);
            m0 += x0; m1 += x1; m2 += x2;
        }
        float invc = 1.0f / (float)cnt;
        m0 *= invc; m1 *= invc; m2 *= invc;
        float S = block_reduce_sum_256(m0 * m0 + m1 * m1 + m2 * m2, red);
        float inv = 1.0f / fmaxf(sqrtf(S), 1e-12f);
        float* o = concat + (size_t)b * 3072 + coff[g] + d;
        o[0] = m0 * inv; o[1] = m1 * inv; o[2] = m2 * inv;
    }
    // assassin: raw into concat, inverse norm into invemb[24]
    size_t abase = (size_t)b * D_ + d;
    float x0 = ldin(assas, abase + 0, isbf);
    float x1 = ldin(assas, abase + 1, isbf);
    float x2 = ldin(assas, abase + 2, isbf);
    float* oc = concat + (size_t)b * 3072 + 768 + d;
    oc[0] = x0; oc[1] = x1; oc[2] = x2;
    float S = block_reduce_sum_256(x0 * x0 + x1 * x1 + x2 * x2, red);
    if (tid == 0) invemb[b * 25 + 24] = 1.0f / fmaxf(sqrtf(S), 1e-12f);
}

// ---------------- split-K GEMM partial: M=64, f32 X, generic W[K][N] ----------------
__global__ __launch_bounds__(256) void gemm_partial_kernel(
    const float* __restrict__ X, const void* __restrict__ W,
    float* __restrict__ P, int K, int N, int CH, const int* __restrict__ dflag) {
    __shared__ float xs[64][68];
    __shared__ float wt[64][68];
    int isbf = *dflag;
    int tid = threadIdx.x;
    int n0 = blockIdx.x * 64;
    int kstart = blockIdx.y * CH;
    int kend = min(K, kstart + CH);
    int tx = tid & 15, ty = tid >> 4;
    float acc[4][4] = {{0.f}};
    for (int k0 = kstart; k0 < kend; k0 += 64) {
        #pragma unroll
        for (int q = 0; q < 4; q++) {
            int e4 = tid + q * 256;
            int m = e4 >> 4, kk = (e4 & 15) * 4;
            float4 v = make_float4(0.f, 0.f, 0.f, 0.f);
            if (k0 + kk < kend) v = *(const float4*)(X + (size_t)m * K + k0 + kk);
            xs[kk + 0][m] = v.x; xs[kk + 1][m] = v.y;
            xs[kk + 2][m] = v.z; xs[kk + 3][m] = v.w;
        }
        #pragma unroll
        for (int q = 0; q < 4; q++) {
            int e4 = tid + q * 256;
            int kk = e4 >> 4, c = (e4 & 15) * 4;
            float4 v = make_float4(0.f, 0.f, 0.f, 0.f);
            if (k0 + kk < kend && n0 + c < N)
                v = ldin4(W, (size_t)(k0 + kk) * N + n0 + c, isbf);
            wt[kk][c + 0] = v.x; wt[kk][c + 1] = v.y;
            wt[kk][c + 2] = v.z; wt[kk][c + 3] = v.w;
        }
        __syncthreads();
        #pragma unroll 16
        for (int kk = 0; kk < 64; kk++) {
            float4 a = *(const float4*)&xs[kk][ty * 4];
            float4 w = *(const float4*)&wt[kk][tx * 4];
            acc[0][0] += a.x * w.x; acc[0][1] += a.x * w.y; acc[0][2] += a.x * w.z; acc[0][3] += a.x * w.w;
            acc[1][0] += a.y * w.x; acc[1][1] += a.y * w.y; acc[1][2] += a.y * w.z; acc[1][3] += a.y * w.w;
            acc[2][0] += a.z * w.x; acc[2][1] += a.z * w.y; acc[2][2] += a.z * w.z; acc[2][3] += a.z * w.w;
            acc[3][0] += a.w * w.x; acc[3][1] += a.w * w.y; acc[3][2] += a.w * w.z; acc[3][3] += a.w * w.w;
        }
        __syncthreads();
    }
    size_t base = (size_t)blockIdx.y * 64 * N;
    int n = n0 + tx * 4;
    if (n < N) {
        #pragma unroll
        for (int i = 0; i < 4; i++) {
            float4 o = make_float4(acc[i][0], acc[i][1], acc[i][2], acc[i][3]);
            *(float4*)(P + base + (size_t)(ty * 4 + i) * N + n) = o;
        }
    }
}

__global__ __launch_bounds__(256) void reduce_act_kernel(
    const float* __restrict__ P, const void* __restrict__ bias,
    float* __restrict__ Y, int N, int KS, int act, const int* __restrict__ dflag) {
    int isbf = *dflag;
    int idx = blockIdx.x * 256 + threadIdx.x;
    if (idx >= 64 * N) return;
    int n = idx % N;
    float s = 0.f;
    for (int ks = 0; ks < KS; ks++) s += P[(size_t)ks * 64 * N + idx];
    s += ldin(bias, n, isbf);
    if (act) s = tanhf(s);
    Y[idx] = s;
}

// normalize model_out rows in-place (f32) and emit f32 to d_out[0:49152]
__global__ __launch_bounds__(256) void norm_mo_kernel(float* __restrict__ mo, float* __restrict__ out) {
    __shared__ float red[256];
    int b = blockIdx.x, tid = threadIdx.x, d = tid * 3;
    float* r_ = mo + (size_t)b * D_ + d;
    float x0 = r_[0], x1 = r_[1], x2 = r_[2];
    float S = block_reduce_sum_256(x0 * x0 + x1 * x1 + x2 * x2, red);
    float inv = 1.0f / fmaxf(sqrtf(S), 1e-12f);
    x0 *= inv; x1 *= inv; x2 *= inv;
    r_[0] = x0; r_[1] = x1; r_[2] = x2;
    float* o = out + (size_t)b * D_ + d;
    o[0] = x0; o[1] = x1; o[2] = x2;
}

// ---------------- sims: mo32(32x768) x vocab^T, fused vocab inv-norm ----------------
__global__ __launch_bounds__(256) void sims_kernel(
    const float* __restrict__ mo32, const void* __restrict__ vocab,
    float* __restrict__ sims, float* __restrict__ invn, int winv,
    const int* __restrict__ dflag) {
    __shared__ float xs[64][36];
    __shared__ float wt[64][68];
    int isbf = *dflag;
    int tid = threadIdx.x;
    int v0 = blockIdx.x * 64;
    int tx = tid & 15, ty = tid >> 4;
    float acc[2][4] = {{0.f}};
    float ssq[4] = {0.f, 0.f, 0.f, 0.f};
    for (int k0 = 0; k0 < 768; k0 += 64) {
        #pragma unroll
        for (int q = 0; q < 2; q++) {
            int e4 = tid + q * 256;
            int m = e4 >> 4, kk = (e4 & 15) * 4;
            float4 v = *(const float4*)(mo32 + (size_t)m * 768 + k0 + kk);
            xs[kk + 0][m] = v.x; xs[kk + 1][m] = v.y;
            xs[kk + 2][m] = v.z; xs[kk + 3][m] = v.w;
        }
        #pragma unroll
        for (int q = 0; q < 4; q++) {
            int e4 = tid + q * 256;
            int r = e4 >> 4, c = (e4 & 15) * 4;
            float4 v = make_float4(0.f, 0.f, 0.f, 0.f);
            if (v0 + r < NVOC)
                v = ldin4(vocab, (size_t)(v0 + r) * 768 + k0 + c, isbf);
            wt[c + 0][r] = v.x; wt[c + 1][r] = v.y;
            wt[c + 2][r] = v.z; wt[c + 3][r] = v.w;
        }
        __syncthreads();
        #pragma unroll 16
        for (int kk = 0; kk < 64; kk++) {
            float2 a = *(const float2*)&xs[kk][ty * 2];
            float4 w = *(const float4*)&wt[kk][tx * 4];
            ssq[0] += w.x * w.x; ssq[1] += w.y * w.y; ssq[2] += w.z * w.z; ssq[3] += w.w * w.w;
            acc[0][0] += a.x * w.x; acc[0][1] += a.x * w.y; acc[0][2] += a.x * w.z; acc[0][3] += a.x * w.w;
            acc[1][0] += a.y * w.x; acc[1][1] += a.y * w.y; acc[1][2] += a.y * w.z; acc[1][3] += a.y * w.w;
        }
        __syncthreads();
    }
    int v = v0 + tx * 4;
    if (v < NVOC) {   // NVOC%64==32, tiles of 4 never straddle
        float inv[4];
        #pragma unroll
        for (int j = 0; j < 4; j++) inv[j] = 1.0f / fmaxf(sqrtf(ssq[j]), 1e-12f);
        #pragma unroll
        for (int i = 0; i < 2; i++) {
            float4 o = make_float4(acc[i][0] * inv[0], acc[i][1] * inv[1],
                                   acc[i][2] * inv[2], acc[i][3] * inv[3]);
            *(float4*)(sims + (size_t)(ty * 2 + i) * NVOC + v) = o;
        }
        if (ty == 0 && winv) *(float4*)(invn + v) = make_float4(inv[0], inv[1], inv[2], inv[3]);
    }
}

// ---------------- exact ordered top-512 per row (jax.lax.top_k semantics) -------------
__device__ void bitonic_desc_u64(unsigned long long* d, int n, int tid, int nt) {
    for (int k = 2; k <= n; k <<= 1) {
        for (int j = k >> 1; j > 0; j >>= 1) {
            for (int i = tid; i < n; i += nt) {
                int ixj = i ^ j;
                if (ixj > i) {
                    unsigned long long a = d[i], b = d[ixj];
                    bool up = ((i & k) == 0);
                    if (up ? (a < b) : (a > b)) { d[i] = b; d[ixj] = a; }
                }
            }
            __syncthreads();
        }
    }
}

__global__ __launch_bounds__(1024) void select512_kernel(
    const float* __restrict__ sims, int* __restrict__ top_idx) {
    __shared__ int hist[4096];
    __shared__ unsigned long long cand[4096];
    __shared__ int ssum[1024];
    __shared__ int s_Tg, s_T, s_cnt;
    int b = blockIdx.x, tid = threadIdx.x;
    const float* row = sims + (size_t)b * NVOC;
    #pragma unroll
    for (int q = 0; q < 4; q++) hist[tid * 4 + q] = 0;
    __syncthreads();
    for (int v = tid; v < NVOC; v += 1024) {
        uint32_t u = fmono(row[v]);
        atomicAdd(&hist[u >> 20], 1);
    }
    __syncthreads();
    int a_ = 0;
    #pragma unroll
    for (int q = 0; q < 4; q++) a_ += hist[tid * 4 + q];
    ssum[tid] = a_; __syncthreads();
    for (int off = 1; off < 1024; off <<= 1) {
        int add = (tid + off < 1024) ? ssum[tid + off] : 0;
        __syncthreads();
        ssum[tid] += add;
        __syncthreads();
    }
    if (ssum[tid] >= VK && (tid == 1023 || ssum[tid + 1] < VK)) s_Tg = tid;
    __syncthreads();
    if (tid == 0) {
        int g = s_Tg;
        int above = (g == 1023) ? 0 : ssum[g + 1];
        int T = g * 4;
        for (int bin = g * 4 + 3; bin >= g * 4; bin--) {
            int c = hist[bin];
            if (above + c >= VK) { T = bin; break; }
            above += c;
        }
        s_T = T; s_cnt = 0;
    }
    __syncthreads();
    uint32_t T = (uint32_t)s_T;
    for (int v = tid; v < NVOC; v += 1024) {
        uint32_t u = fmono(row[v]);
        if ((u >> 20) >= T) {
            int p = atomicAdd(&s_cnt, 1);
            if (p < 4096) cand[p] = ((unsigned long long)u << 32) | (uint32_t)(~v);
        }
    }
    __syncthreads();
    int total = min(s_cnt, 4096);
    for (int i = tid; i < 4096; i += 1024)
        if (i >= total) cand[i] = 0ull;
    __syncthreads();
    bitonic_desc_u64(cand, 4096, tid, 1024);
    if (tid < VK) top_idx[(size_t)b * VK + tid] = (int)(~(uint32_t)(cand[tid] & 0xFFFFFFFFull));
}

// ---------------- per-candidate 25 sims -> primary/secondary -> tot_reward ------------
// NEW STRUCTURE: one candidate per lane (no cross-lane reduce), 25 normalized
// embeddings staged once per block in LDS (d split into two 384-halves, 37.5 KB).
// All LDS reads are wave-uniform broadcasts; each lane streams its own vocab row.
__global__ __launch_bounds__(128) void tot_kernel(
    const int* __restrict__ top_idx, const void* __restrict__ vocab,
    const float* __restrict__ invn, const float* __restrict__ invemb,
    const void* __restrict__ pos, const void* __restrict__ neg,
    const void* __restrict__ neut, const void* __restrict__ assas,
    float* __restrict__ tot, const int* __restrict__ dflag) {
    __shared__ float E[25 * 384];          // normalized emb half-rows: 37.5 KB
    int isbf = *dflag;
    int b = blockIdx.y;
    int j = blockIdx.x * 128 + threadIdx.x;    // blockIdx.x in [0,4): 128 j per block
    int v = top_idx[(size_t)b * VK + j];
    if ((unsigned)v >= (unsigned)NVOC) v = 0;
    size_t vbase = (size_t)v * D_;
    float p[25];
    #pragma unroll
    for (int i = 0; i < 25; i++) p[i] = 0.f;

    for (int h = 0; h < 2; h++) {
        __syncthreads();                   // protect E from previous-half readers
        // stage 25 x 384 floats (2400 float4), normalization fused into the store
        for (int u = threadIdx.x; u < 2400; u += 128) {
            int i = u / 96;
            int c = (u - i * 96) * 4;
            const void* ep; size_t eb;
            if (i < 9)       { ep = pos;   eb = ((size_t)b * 9 + i) * D_; }
            else if (i < 17) { ep = neg;   eb = ((size_t)b * 8 + (i - 9)) * D_; }
            else if (i < 24) { ep = neut;  eb = ((size_t)b * 7 + (i - 17)) * D_; }
            else             { ep = assas; eb = (size_t)b * D_; }
            float4 x = ldin4(ep, eb + h * 384 + c, isbf);
            float s = invemb[b * 25 + i];
            E[i * 384 + c + 0] = x.x * s;
            E[i * 384 + c + 1] = x.y * s;
            E[i * 384 + c + 2] = x.z * s;
            E[i * 384 + c + 3] = x.w * s;
        }
        __syncthreads();
        // each lane: stream own vocab row half, 25 accumulators in registers
        for (int c = 0; c < 384; c += 4) {
            float4 w = ldin4(vocab, vbase + h * 384 + c, isbf);
            #pragma unroll
            for (int i = 0; i < 25; i++) {
                float4 e = *(const float4*)&E[i * 384 + c];
                p[i] += w.x * e.x + w.y * e.y + w.z * e.z + w.w * e.w;
            }
        }
    }

    float invv = invn[v];
    #pragma unroll
    for (int i = 0; i < 25; i++) p[i] *= invv;
    float mx = -1e30f; int am = 9;
    #pragma unroll
    for (int i = 9; i < 25; i++) if (p[i] > mx) { mx = p[i]; am = i; }
    int primary = 0;
    #pragma unroll
    for (int i = 0; i < 9; i++) primary += (p[i] >= mx) ? 1 : 0;
    float secondary = (am == 24) ? -10.0f : ((am >= 17) ? 1.0f : 0.0f);
    tot[(size_t)b * VK + j] = (float)primary + secondary;
}

// ---------------- top/bottom 256 of tot (exact tie semantics) ----------------
__global__ __launch_bounds__(256) void sort512_kernel(
    const float* __restrict__ tot, int* __restrict__ idx_max, int* __restrict__ idx_min) {
    __shared__ unsigned long long key[512];
    int b = blockIdx.x, tid = threadIdx.x;
    for (int pass = 0; pass < 2; pass++) {
        for (int j = tid; j < 512; j += 256) {
            uint32_t m = fmono(tot[(size_t)b * VK + j]);
            if (pass) m = ~m;
            key[j] = ((unsigned long long)m << 32) | (uint32_t)(511 - j);
        }
        __syncthreads();
        bitonic_desc_u64(key, 512, tid, 256);
        int* dst = pass ? idx_min : idx_max;
        if (tid < 256) dst[(size_t)b * KH + tid] = 511 - (int)(key[tid] & 0xFFFFFFFFull);
        __syncthreads();
    }
}

// ---------------- gather + mean + normalize; search_embedding bit-exact copy ----------
__global__ __launch_bounds__(256) void pool_kernel(
    const int* __restrict__ top_idx, const int* __restrict__ idx_max,
    const int* __restrict__ idx_min, const void* __restrict__ vocab,
    float* __restrict__ out, const int* __restrict__ dflag) {
    __shared__ float red[256];
    int isbf = *dflag;
    int b = blockIdx.x, s = blockIdx.y, tid = threadIdx.x;
    const int* sel = s ? idx_min : idx_max;
    int d = tid * 3;
    float a0 = 0.f, a1 = 0.f, a2 = 0.f;
    for (int r = 0; r < 256; r++) {
        int v = top_idx[(size_t)b * VK + sel[(size_t)b * KH + r]];
        if ((unsigned)v >= (unsigned)NVOC) v = 0;
        size_t vb = (size_t)v * D_ + d;
        a0 += ldin(vocab, vb + 0, isbf);
        a1 += ldin(vocab, vb + 1, isbf);
        a2 += ldin(vocab, vb + 2, isbf);
    }
    a0 *= (1.0f / 256.0f); a1 *= (1.0f / 256.0f); a2 *= (1.0f / 256.0f);
    float S = block_reduce_sum_256(a0 * a0 + a1 * a1 + a2 * a2, red);
    float inv = 1.0f / fmaxf(sqrtf(S), 1e-12f);
    float* o = out + (size_t)(2 + s) * (B_ * D_) + (size_t)b * D_ + d;
    o[0] = a0 * inv;
    o[1] = a1 * inv;
    o[2] = a2 * inv;
    if (s == 0) {
        int v0 = top_idx[(size_t)b * VK + sel[(size_t)b * KH + 0]];
        if ((unsigned)v0 >= (unsigned)NVOC) v0 = 0;
        size_t vb = (size_t)v0 * D_ + d;
        float* so = out + (size_t)(B_ * D_) + (size_t)b * D_ + d;
        so[0] = ldin(vocab, vb + 0, isbf);
        so[1] = ldin(vocab, vb + 1, isbf);
        so[2] = ldin(vocab, vb + 2, isbf);
    }
}

extern "C" void kernel_launch(void* const* d_in, const int* in_sizes, int n_in,
                              void* d_out, int out_size, void* d_ws, size_t ws_size,
                              hipStream_t stream) {
    const void* pos   = d_in[0];
    const void* neg   = d_in[1];
    const void* neut  = d_in[2];
    const void* assas = d_in[3];
    const void* vocab = d_in[4];
    const void* W1 = d_in[5];  const void* b1 = d_in[6];
    const void* W2 = d_in[7];  const void* b2 = d_in[8];
    const void* W3 = d_in[9];  const void* b3 = d_in[10];
    const void* W4 = d_in[11]; const void* b4 = d_in[12];
    float* out = (float*)d_out;

    // ws layout (floats), ~15.9 MB
    float* ws = (float*)d_ws;
    float* concat = ws;                          // 196608
    float* h1     = concat + 196608;             // 147456
    float* h2     = h1 + 147456;                 // 108800
    float* h3     = h2 + 108800;                 //  64000
    float* mo     = h3 + 64000;                  //  49152
    float* invn   = mo + 49152;                  // 100000
    float* invemb = invn + 100000;               //   1600
    float* simsPb = invemb + 1600;               // 3200000 (union: Pbuf + 32-row sims)
    int* top_idx  = (int*)(simsPb + 3200000);    // 32768
    float* tot    = (float*)(top_idx + 64 * VK); // 32768
    int* imax     = (int*)(tot + 64 * VK);       // 16384
    int* imin     = imax + 64 * KH;              // 16384
    int* dflag    = imin + 64 * KH;              // 1

    detect_kernel<<<1, 64, 0, stream>>>(vocab, dflag);

    prep_kernel<<<64, 256, 0, stream>>>(pos, neg, neut, assas, concat, invemb, dflag);

    // L1: 3072 -> 2304, tanh   (CH=384, KS=8)
    gemm_partial_kernel<<<dim3(36, 8), 256, 0, stream>>>(concat, W1, simsPb, 3072, 2304, 384, dflag);
    reduce_act_kernel<<<576, 256, 0, stream>>>(simsPb, b1, h1, 2304, 8, 1, dflag);
    // L2: 2304 -> 1700, tanh   (CH=256, KS=9)
    gemm_partial_kernel<<<dim3(27, 9), 256, 0, stream>>>(h1, W2, simsPb, 2304, 1700, 256, dflag);
    reduce_act_kernel<<<425, 256, 0, stream>>>(simsPb, b2, h2, 1700, 9, 1, dflag);
    // L3: 1700 -> 1000, tanh   (CH=192, KS=9)
    gemm_partial_kernel<<<dim3(16, 9), 256, 0, stream>>>(h2, W3, simsPb, 1700, 1000, 192, dflag);
    reduce_act_kernel<<<250, 256, 0, stream>>>(simsPb, b3, h3, 1000, 9, 1, dflag);
    // L4: 1000 -> 768, no act  (CH=128, KS=8)
    gemm_partial_kernel<<<dim3(12, 8), 256, 0, stream>>>(h3, W4, simsPb, 1000, 768, 128, dflag);
    reduce_act_kernel<<<192, 256, 0, stream>>>(simsPb, b4, mo, 768, 8, 0, dflag);

    norm_mo_kernel<<<64, 256, 0, stream>>>(mo, out);

    // sims + top-512 in two 32-row passes (reuses simsPb region)
    for (int pass = 0; pass < 2; pass++) {
        sims_kernel<<<1563, 256, 0, stream>>>(mo + (size_t)pass * 32 * D_, vocab,
                                              simsPb, invn, pass == 0, dflag);
        select512_kernel<<<32, 1024, 0, stream>>>(simsPb, top_idx + (size_t)pass * 32 * VK);
    }

    // one candidate per lane; 25 normalized embeddings staged in LDS per block
    tot_kernel<<<dim3(4, 64), 128, 0, stream>>>(top_idx, vocab, invn, invemb,
                                                pos, neg, neut, assas, tot, dflag);

    sort512_kernel<<<64, 256, 0, stream>>>(tot, imax, imin);

    pool_kernel<<<dim3(64, 2), 256, 0, stream>>>(top_idx, imax, imin, vocab, out, dflag);
}

// Round 3
// 1083.661 us; speedup vs baseline: 4.0442x; 1.2078x over previous
//
#include <hip/hip_runtime.h>
#include <hip/hip_bf16.h>
#include <stdint.h>

#define B_    64
#define D_    768
#define NVOC  100000
#define VK    512
#define KH    256

__device__ __forceinline__ float b2f_raw(unsigned short u) {
    return __uint_as_float(((unsigned int)u) << 16);
}
// dtype-generic input load: isbf=1 -> bf16, else f32
__device__ __forceinline__ float ldin(const void* p, size_t i, int isbf) {
    return isbf ? b2f_raw(((const unsigned short*)p)[i]) : ((const float*)p)[i];
}
__device__ __forceinline__ float4 ldin4(const void* p, size_t i, int isbf) {
    if (isbf) {
        ushort4 r = *(const ushort4*)((const unsigned short*)p + i);
        return make_float4(b2f_raw(r.x), b2f_raw(r.y), b2f_raw(r.z), b2f_raw(r.w));
    }
    return *(const float4*)((const float*)p + i);
}
// monotonic float->uint map (order-preserving)
__device__ __forceinline__ uint32_t fmono(float x) {
    uint32_t u = __float_as_uint(x);
    return u ^ (uint32_t)((((int32_t)u) >> 31) | 0x80000000u);
}

__device__ __forceinline__ float block_reduce_sum_256(float v, float* red) {
    int tid = threadIdx.x;
    red[tid] = v; __syncthreads();
    #pragma unroll
    for (int s = 128; s > 0; s >>= 1) {
        if (tid < s) red[tid] += red[tid + s];
        __syncthreads();
    }
    float r = red[0]; __syncthreads();
    return r;
}

// ---------------- dtype detector: f32 N(0,1) data vs bf16 data misread as f32 --------
__global__ void detect_kernel(const void* vocab, int* flag) {
    if (threadIdx.x == 0 && blockIdx.x == 0) {
        const float* vf = (const float*)vocab;
        int sane = 0;
        for (int i = 0; i < 256; i++) {
            float a = fabsf(vf[i]);
            if (a > 1e-4f && a < 64.0f) sane++;
        }
        *flag = (sane >= 200) ? 0 : 1;   // 0 = f32 inputs, 1 = bf16 inputs
    }
}

// ---------------- prep: pools into concat + per-embedding inverse norms ----------------
// invemb layout: [b][25]; i=0..8 pos, 9..16 neg, 17..23 neut, 24 assas
// concat layout: [b][3072] = [neg_pool | assas_raw | neut_pool | pos_pool]
__global__ __launch_bounds__(256) void prep_kernel(
    const void* __restrict__ pos, const void* __restrict__ neg,
    const void* __restrict__ neut, const void* __restrict__ assas,
    float* __restrict__ concat, float* __restrict__ invemb,
    const int* __restrict__ dflag) {
    __shared__ float red[256];
    int isbf = *dflag;
    int b = blockIdx.x, tid = threadIdx.x;
    int d = tid * 3;
    const void* srcs[3] = {pos, neg, neut};
    const int cnts[3]  = {9, 8, 7};
    const int ieoff[3] = {0, 9, 17};
    const int coff[3]  = {2304, 0, 1536};
    for (int g = 0; g < 3; g++) {
        float m0 = 0.f, m1 = 0.f, m2 = 0.f;
        int cnt = cnts[g];
        for (int m = 0; m < cnt; m++) {
            size_t base = ((size_t)b * cnt + m) * D_ + d;
            float x0 = ldin(srcs[g], base + 0, isbf);
            float x1 = ldin(srcs[g], base + 1, isbf);
            float x2 = ldin(srcs[g], base + 2, isbf);
            float S = block_reduce_sum_256(x0 * x0 + x1 * x1 + x2 * x2, red);
            if (tid == 0)
                invemb[b * 25 + ieoff[g] + m] = 1.0f / fmaxf(sqrtf(S), 1e-12f);
            m0 += x0; m1 += x1; m2 += x2;
        }
        float invc = 1.0f / (float)cnt;
        m0 *= invc; m1 *= invc; m2 *= invc;
        float S = block_reduce_sum_256(m0 * m0 + m1 * m1 + m2 * m2, red);
        float inv = 1.0f / fmaxf(sqrtf(S), 1e-12f);
        float* o = concat + (size_t)b * 3072 + coff[g] + d;
        o[0] = m0 * inv; o[1] = m1 * inv; o[2] = m2 * inv;
    }
    // assassin: raw into concat, inverse norm into invemb[24]
    size_t abase = (size_t)b * D_ + d;
    float x0 = ldin(assas, abase + 0, isbf);
    float x1 = ldin(assas, abase + 1, isbf);
    float x2 = ldin(assas, abase + 2, isbf);
    float* oc = concat + (size_t)b * 3072 + 768 + d;
    oc[0] = x0; oc[1] = x1; oc[2] = x2;
    float S = block_reduce_sum_256(x0 * x0 + x1 * x1 + x2 * x2, red);
    if (tid == 0) invemb[b * 25 + 24] = 1.0f / fmaxf(sqrtf(S), 1e-12f);
}

// ---------------- split-K GEMM partial: M=64, f32 X, generic W[K][N] ----------------
__global__ __launch_bounds__(256) void gemm_partial_kernel(
    const float* __restrict__ X, const void* __restrict__ W,
    float* __restrict__ P, int K, int N, int CH, const int* __restrict__ dflag) {
    __shared__ float xs[64][68];
    __shared__ float wt[64][68];
    int isbf = *dflag;
    int tid = threadIdx.x;
    int n0 = blockIdx.x * 64;
    int kstart = blockIdx.y * CH;
    int kend = min(K, kstart + CH);
    int tx = tid & 15, ty = tid >> 4;
    float acc[4][4] = {{0.f}};
    for (int k0 = kstart; k0 < kend; k0 += 64) {
        #pragma unroll
        for (int q = 0; q < 4; q++) {
            int e4 = tid + q * 256;
            int m = e4 >> 4, kk = (e4 & 15) * 4;
            float4 v = make_float4(0.f, 0.f, 0.f, 0.f);
            if (k0 + kk < kend) v = *(const float4*)(X + (size_t)m * K + k0 + kk);
            xs[kk + 0][m] = v.x; xs[kk + 1][m] = v.y;
            xs[kk + 2][m] = v.z; xs[kk + 3][m] = v.w;
        }
        #pragma unroll
        for (int q = 0; q < 4; q++) {
            int e4 = tid + q * 256;
            int kk = e4 >> 4, c = (e4 & 15) * 4;
            float4 v = make_float4(0.f, 0.f, 0.f, 0.f);
            if (k0 + kk < kend && n0 + c < N)
                v = ldin4(W, (size_t)(k0 + kk) * N + n0 + c, isbf);
            wt[kk][c + 0] = v.x; wt[kk][c + 1] = v.y;
            wt[kk][c + 2] = v.z; wt[kk][c + 3] = v.w;
        }
        __syncthreads();
        #pragma unroll 16
        for (int kk = 0; kk < 64; kk++) {
            float4 a = *(const float4*)&xs[kk][ty * 4];
            float4 w = *(const float4*)&wt[kk][tx * 4];
            acc[0][0] += a.x * w.x; acc[0][1] += a.x * w.y; acc[0][2] += a.x * w.z; acc[0][3] += a.x * w.w;
            acc[1][0] += a.y * w.x; acc[1][1] += a.y * w.y; acc[1][2] += a.y * w.z; acc[1][3] += a.y * w.w;
            acc[2][0] += a.z * w.x; acc[2][1] += a.z * w.y; acc[2][2] += a.z * w.z; acc[2][3] += a.z * w.w;
            acc[3][0] += a.w * w.x; acc[3][1] += a.w * w.y; acc[3][2] += a.w * w.z; acc[3][3] += a.w * w.w;
        }
        __syncthreads();
    }
    size_t base = (size_t)blockIdx.y * 64 * N;
    int n = n0 + tx * 4;
    if (n < N) {
        #pragma unroll
        for (int i = 0; i < 4; i++) {
            float4 o = make_float4(acc[i][0], acc[i][1], acc[i][2], acc[i][3]);
            *(float4*)(P + base + (size_t)(ty * 4 + i) * N + n) = o;
        }
    }
}

__global__ __launch_bounds__(256) void reduce_act_kernel(
    const float* __restrict__ P, const void* __restrict__ bias,
    float* __restrict__ Y, int N, int KS, int act, const int* __restrict__ dflag) {
    int isbf = *dflag;
    int idx = blockIdx.x * 256 + threadIdx.x;
    if (idx >= 64 * N) return;
    int n = idx % N;
    float s = 0.f;
    for (int ks = 0; ks < KS; ks++) s += P[(size_t)ks * 64 * N + idx];
    s += ldin(bias, n, isbf);
    if (act) s = tanhf(s);
    Y[idx] = s;
}

// normalize model_out rows in-place (f32), emit f32 to d_out[0:49152], and
// optionally write transposed copy moT[768][64] for the single-pass sims kernel
__global__ __launch_bounds__(256) void norm_mo_kernel(
    float* __restrict__ mo, float* __restrict__ out, float* __restrict__ moTp) {
    __shared__ float red[256];
    int b = blockIdx.x, tid = threadIdx.x, d = tid * 3;
    float* r_ = mo + (size_t)b * D_ + d;
    float x0 = r_[0], x1 = r_[1], x2 = r_[2];
    float S = block_reduce_sum_256(x0 * x0 + x1 * x1 + x2 * x2, red);
    float inv = 1.0f / fmaxf(sqrtf(S), 1e-12f);
    x0 *= inv; x1 *= inv; x2 *= inv;
    r_[0] = x0; r_[1] = x1; r_[2] = x2;
    float* o = out + (size_t)b * D_ + d;
    o[0] = x0; o[1] = x1; o[2] = x2;
    if (moTp) {
        moTp[(size_t)(d + 0) * 64 + b] = x0;
        moTp[(size_t)(d + 1) * 64 + b] = x1;
        moTp[(size_t)(d + 2) * 64 + b] = x2;
    }
}

// ---------------- sims64: ALL 64 rows x vocab^T in ONE vocab pass --------------------
// moT is mo transposed [768][64]. wt tile stored transposed with XOR swizzle
// col' = r ^ (((row>>2)&7)<<2): stores 2-way (free), reads contiguous float4.
__global__ __launch_bounds__(256) void sims64_kernel(
    const float* __restrict__ moT, const void* __restrict__ vocab,
    float* __restrict__ sims, float* __restrict__ invn,
    const int* __restrict__ dflag) {
    __shared__ float xs[64 * 64];
    __shared__ float wt[64 * 64];
    int isbf = *dflag;
    int tid = threadIdx.x;
    int v0 = blockIdx.x * 64;
    int tx = tid & 15, ty = tid >> 4;
    float acc[4][4] = {{0.f}};
    float ssq[4] = {0.f, 0.f, 0.f, 0.f};
    for (int k0 = 0; k0 < 768; k0 += 64) {
        // stage xs[k][m] from moT (row-major, no transpose, no conflicts)
        #pragma unroll
        for (int q = 0; q < 4; q++) {
            int e4 = tid + q * 256;
            int kr = e4 >> 4, m4 = (e4 & 15) * 4;
            float4 v = *(const float4*)(moT + (size_t)(k0 + kr) * 64 + m4);
            *(float4*)&xs[kr * 64 + m4] = v;
        }
        // stage wt[k][v] transposed from vocab with XOR swizzle
        #pragma unroll
        for (int q = 0; q < 4; q++) {
            int e4 = tid + q * 256;
            int r = e4 >> 4, kq = e4 & 15, c = kq * 4;
            float4 v = make_float4(0.f, 0.f, 0.f, 0.f);
            if (v0 + r < NVOC)
                v = ldin4(vocab, (size_t)(v0 + r) * 768 + k0 + c, isbf);
            int colp = r ^ ((kq & 7) << 2);
            wt[(c + 0) * 64 + colp] = v.x;
            wt[(c + 1) * 64 + colp] = v.y;
            wt[(c + 2) * 64 + colp] = v.z;
            wt[(c + 3) * 64 + colp] = v.w;
        }
        __syncthreads();
        #pragma unroll 16
        for (int kk = 0; kk < 64; kk++) {
            float4 a = *(const float4*)&xs[kk * 64 + ty * 4];
            float4 w = *(const float4*)&wt[kk * 64 + ((tx * 4) ^ (((kk >> 2) & 7) << 2))];
            ssq[0] += w.x * w.x; ssq[1] += w.y * w.y; ssq[2] += w.z * w.z; ssq[3] += w.w * w.w;
            acc[0][0] += a.x * w.x; acc[0][1] += a.x * w.y; acc[0][2] += a.x * w.z; acc[0][3] += a.x * w.w;
            acc[1][0] += a.y * w.x; acc[1][1] += a.y * w.y; acc[1][2] += a.y * w.z; acc[1][3] += a.y * w.w;
            acc[2][0] += a.z * w.x; acc[2][1] += a.z * w.y; acc[2][2] += a.z * w.z; acc[2][3] += a.z * w.w;
            acc[3][0] += a.w * w.x; acc[3][1] += a.w * w.y; acc[3][2] += a.w * w.z; acc[3][3] += a.w * w.w;
        }
        __syncthreads();
    }
    int v = v0 + tx * 4;
    if (v < NVOC) {   // NVOC%64==32, quads never straddle
        float inv[4];
        #pragma unroll
        for (int j = 0; j < 4; j++) inv[j] = 1.0f / fmaxf(sqrtf(ssq[j]), 1e-12f);
        #pragma unroll
        for (int i = 0; i < 4; i++) {
            float4 o = make_float4(acc[i][0] * inv[0], acc[i][1] * inv[1],
                                   acc[i][2] * inv[2], acc[i][3] * inv[3]);
            *(float4*)(sims + (size_t)(ty * 4 + i) * NVOC + v) = o;
        }
        if (ty == 0) *(float4*)(invn + v) = make_float4(inv[0], inv[1], inv[2], inv[3]);
    }
}

// ---------------- sims (fallback 2-pass, 32 rows): mo32 x vocab^T --------------------
__global__ __launch_bounds__(256) void sims_kernel(
    const float* __restrict__ mo32, const void* __restrict__ vocab,
    float* __restrict__ sims, float* __restrict__ invn, int winv,
    const int* __restrict__ dflag) {
    __shared__ float xs[64][36];
    __shared__ float wt[64][68];
    int isbf = *dflag;
    int tid = threadIdx.x;
    int v0 = blockIdx.x * 64;
    int tx = tid & 15, ty = tid >> 4;
    float acc[2][4] = {{0.f}};
    float ssq[4] = {0.f, 0.f, 0.f, 0.f};
    for (int k0 = 0; k0 < 768; k0 += 64) {
        #pragma unroll
        for (int q = 0; q < 2; q++) {
            int e4 = tid + q * 256;
            int m = e4 >> 4, kk = (e4 & 15) * 4;
            float4 v = *(const float4*)(mo32 + (size_t)m * 768 + k0 + kk);
            xs[kk + 0][m] = v.x; xs[kk + 1][m] = v.y;
            xs[kk + 2][m] = v.z; xs[kk + 3][m] = v.w;
        }
        #pragma unroll
        for (int q = 0; q < 4; q++) {
            int e4 = tid + q * 256;
            int r = e4 >> 4, c = (e4 & 15) * 4;
            float4 v = make_float4(0.f, 0.f, 0.f, 0.f);
            if (v0 + r < NVOC)
                v = ldin4(vocab, (size_t)(v0 + r) * 768 + k0 + c, isbf);
            wt[c + 0][r] = v.x; wt[c + 1][r] = v.y;
            wt[c + 2][r] = v.z; wt[c + 3][r] = v.w;
        }
        __syncthreads();
        #pragma unroll 16
        for (int kk = 0; kk < 64; kk++) {
            float2 a = *(const float2*)&xs[kk][ty * 2];
            float4 w = *(const float4*)&wt[kk][tx * 4];
            ssq[0] += w.x * w.x; ssq[1] += w.y * w.y; ssq[2] += w.z * w.z; ssq[3] += w.w * w.w;
            acc[0][0] += a.x * w.x; acc[0][1] += a.x * w.y; acc[0][2] += a.x * w.z; acc[0][3] += a.x * w.w;
            acc[1][0] += a.y * w.x; acc[1][1] += a.y * w.y; acc[1][2] += a.y * w.z; acc[1][3] += a.y * w.w;
        }
        __syncthreads();
    }
    int v = v0 + tx * 4;
    if (v < NVOC) {
        float inv[4];
        #pragma unroll
        for (int j = 0; j < 4; j++) inv[j] = 1.0f / fmaxf(sqrtf(ssq[j]), 1e-12f);
        #pragma unroll
        for (int i = 0; i < 2; i++) {
            float4 o = make_float4(acc[i][0] * inv[0], acc[i][1] * inv[1],
                                   acc[i][2] * inv[2], acc[i][3] * inv[3]);
            *(float4*)(sims + (size_t)(ty * 2 + i) * NVOC + v) = o;
        }
        if (ty == 0 && winv) *(float4*)(invn + v) = make_float4(inv[0], inv[1], inv[2], inv[3]);
    }
}

// ---------------- exact ordered top-512 per row (jax.lax.top_k semantics) -------------
__device__ void bitonic_desc_u64(unsigned long long* d, int n, int tid, int nt) {
    for (int k = 2; k <= n; k <<= 1) {
        for (int j = k >> 1; j > 0; j >>= 1) {
            for (int i = tid; i < n; i += nt) {
                int ixj = i ^ j;
                if (ixj > i) {
                    unsigned long long a = d[i], b = d[ixj];
                    bool up = ((i & k) == 0);
                    if (up ? (a < b) : (a > b)) { d[i] = b; d[ixj] = a; }
                }
            }
            __syncthreads();
        }
    }
}

__global__ __launch_bounds__(1024) void select512_kernel(
    const float* __restrict__ sims, int* __restrict__ top_idx) {
    __shared__ int hist[4096];
    __shared__ unsigned long long cand[4096];
    __shared__ int ssum[1024];
    __shared__ int s_Tg, s_T, s_cnt;
    int b = blockIdx.x, tid = threadIdx.x;
    const float* row = sims + (size_t)b * NVOC;
    #pragma unroll
    for (int q = 0; q < 4; q++) hist[tid * 4 + q] = 0;
    __syncthreads();
    for (int v = tid; v < NVOC; v += 1024) {
        uint32_t u = fmono(row[v]);
        atomicAdd(&hist[u >> 20], 1);
    }
    __syncthreads();
    int a_ = 0;
    #pragma unroll
    for (int q = 0; q < 4; q++) a_ += hist[tid * 4 + q];
    ssum[tid] = a_; __syncthreads();
    for (int off = 1; off < 1024; off <<= 1) {
        int add = (tid + off < 1024) ? ssum[tid + off] : 0;
        __syncthreads();
        ssum[tid] += add;
        __syncthreads();
    }
    if (ssum[tid] >= VK && (tid == 1023 || ssum[tid + 1] < VK)) s_Tg = tid;
    __syncthreads();
    if (tid == 0) {
        int g = s_Tg;
        int above = (g == 1023) ? 0 : ssum[g + 1];
        int T = g * 4;
        for (int bin = g * 4 + 3; bin >= g * 4; bin--) {
            int c = hist[bin];
            if (above + c >= VK) { T = bin; break; }
            above += c;
        }
        s_T = T; s_cnt = 0;
    }
    __syncthreads();
    uint32_t T = (uint32_t)s_T;
    for (int v = tid; v < NVOC; v += 1024) {
        uint32_t u = fmono(row[v]);
        if ((u >> 20) >= T) {
            int p = atomicAdd(&s_cnt, 1);
            if (p < 4096) cand[p] = ((unsigned long long)u << 32) | (uint32_t)(~v);
        }
    }
    __syncthreads();
    int total = min(s_cnt, 4096);
    for (int i = tid; i < 4096; i += 1024)
        if (i >= total) cand[i] = 0ull;
    __syncthreads();
    bitonic_desc_u64(cand, 4096, tid, 1024);
    if (tid < VK) top_idx[(size_t)b * VK + tid] = (int)(~(uint32_t)(cand[tid] & 0xFFFFFFFFull));
}

// ---------------- per-candidate 25 sims -> primary/secondary -> tot_reward ------------
// one candidate per lane (no cross-lane reduce), 25 normalized embeddings staged
// once per block in LDS (d split into two 384-halves, 37.5 KB).
__global__ __launch_bounds__(128) void tot_kernel(
    const int* __restrict__ top_idx, const void* __restrict__ vocab,
    const float* __restrict__ invn, const float* __restrict__ invemb,
    const void* __restrict__ pos, const void* __restrict__ neg,
    const void* __restrict__ neut, const void* __restrict__ assas,
    float* __restrict__ tot, const int* __restrict__ dflag) {
    __shared__ float E[25 * 384];          // normalized emb half-rows: 37.5 KB
    int isbf = *dflag;
    int b = blockIdx.y;
    int j = blockIdx.x * 128 + threadIdx.x;    // blockIdx.x in [0,4): 128 j per block
    int v = top_idx[(size_t)b * VK + j];
    if ((unsigned)v >= (unsigned)NVOC) v = 0;
    size_t vbase = (size_t)v * D_;
    float p[25];
    #pragma unroll
    for (int i = 0; i < 25; i++) p[i] = 0.f;

    for (int h = 0; h < 2; h++) {
        __syncthreads();                   // protect E from previous-half readers
        // stage 25 x 384 floats (2400 float4), normalization fused into the store
        for (int u = threadIdx.x; u < 2400; u += 128) {
            int i = u / 96;
            int c = (u - i * 96) * 4;
            const void* ep; size_t eb;
            if (i < 9)       { ep = pos;   eb = ((size_t)b * 9 + i) * D_; }
            else if (i < 17) { ep = neg;   eb = ((size_t)b * 8 + (i - 9)) * D_; }
            else if (i < 24) { ep = neut;  eb = ((size_t)b * 7 + (i - 17)) * D_; }
            else             { ep = assas; eb = (size_t)b * D_; }
            float4 x = ldin4(ep, eb + h * 384 + c, isbf);
            float s = invemb[b * 25 + i];
            E[i * 384 + c + 0] = x.x * s;
            E[i * 384 + c + 1] = x.y * s;
            E[i * 384 + c + 2] = x.z * s;
            E[i * 384 + c + 3] = x.w * s;
        }
        __syncthreads();
        // each lane: stream own vocab row half, 25 accumulators in registers
        for (int c = 0; c < 384; c += 4) {
            float4 w = ldin4(vocab, vbase + h * 384 + c, isbf);
            #pragma unroll
            for (int i = 0; i < 25; i++) {
                float4 e = *(const float4*)&E[i * 384 + c];
                p[i] += w.x * e.x + w.y * e.y + w.z * e.z + w.w * e.w;
            }
        }
    }

    float invv = invn[v];
    #pragma unroll
    for (int i = 0; i < 25; i++) p[i] *= invv;
    float mx = -1e30f; int am = 9;
    #pragma unroll
    for (int i = 9; i < 25; i++) if (p[i] > mx) { mx = p[i]; am = i; }
    int primary = 0;
    #pragma unroll
    for (int i = 0; i < 9; i++) primary += (p[i] >= mx) ? 1 : 0;
    float secondary = (am == 24) ? -10.0f : ((am >= 17) ? 1.0f : 0.0f);
    tot[(size_t)b * VK + j] = (float)primary + secondary;
}

// ---------------- top/bottom 256 of tot (exact tie semantics) ----------------
__global__ __launch_bounds__(256) void sort512_kernel(
    const float* __restrict__ tot, int* __restrict__ idx_max, int* __restrict__ idx_min) {
    __shared__ unsigned long long key[512];
    int b = blockIdx.x, tid = threadIdx.x;
    for (int pass = 0; pass < 2; pass++) {
        for (int j = tid; j < 512; j += 256) {
            uint32_t m = fmono(tot[(size_t)b * VK + j]);
            if (pass) m = ~m;
            key[j] = ((unsigned long long)m << 32) | (uint32_t)(511 - j);
        }
        __syncthreads();
        bitonic_desc_u64(key, 512, tid, 256);
        int* dst = pass ? idx_min : idx_max;
        if (tid < 256) dst[(size_t)b * KH + tid] = 511 - (int)(key[tid] & 0xFFFFFFFFull);
        __syncthreads();
    }
}

// ---------------- gather + mean + normalize; search_embedding bit-exact copy ----------
__global__ __launch_bounds__(256) void pool_kernel(
    const int* __restrict__ top_idx, const int* __restrict__ idx_max,
    const int* __restrict__ idx_min, const void* __restrict__ vocab,
    float* __restrict__ out, const int* __restrict__ dflag) {
    __shared__ float red[256];
    int isbf = *dflag;
    int b = blockIdx.x, s = blockIdx.y, tid = threadIdx.x;
    const int* sel = s ? idx_min : idx_max;
    int d = tid * 3;
    float a0 = 0.f, a1 = 0.f, a2 = 0.f;
    for (int r = 0; r < 256; r++) {
        int v = top_idx[(size_t)b * VK + sel[(size_t)b * KH + r]];
        if ((unsigned)v >= (unsigned)NVOC) v = 0;
        size_t vb = (size_t)v * D_ + d;
        a0 += ldin(vocab, vb + 0, isbf);
        a1 += ldin(vocab, vb + 1, isbf);
        a2 += ldin(vocab, vb + 2, isbf);
    }
    a0 *= (1.0f / 256.0f); a1 *= (1.0f / 256.0f); a2 *= (1.0f / 256.0f);
    float S = block_reduce_sum_256(a0 * a0 + a1 * a1 + a2 * a2, red);
    float inv = 1.0f / fmaxf(sqrtf(S), 1e-12f);
    float* o = out + (size_t)(2 + s) * (B_ * D_) + (size_t)b * D_ + d;
    o[0] = a0 * inv;
    o[1] = a1 * inv;
    o[2] = a2 * inv;
    if (s == 0) {
        int v0 = top_idx[(size_t)b * VK + sel[(size_t)b * KH + 0]];
        if ((unsigned)v0 >= (unsigned)NVOC) v0 = 0;
        size_t vb = (size_t)v0 * D_ + d;
        float* so = out + (size_t)(B_ * D_) + (size_t)b * D_ + d;
        so[0] = ldin(vocab, vb + 0, isbf);
        so[1] = ldin(vocab, vb + 1, isbf);
        so[2] = ldin(vocab, vb + 2, isbf);
    }
}

extern "C" void kernel_launch(void* const* d_in, const int* in_sizes, int n_in,
                              void* d_out, int out_size, void* d_ws, size_t ws_size,
                              hipStream_t stream) {
    const void* pos   = d_in[0];
    const void* neg   = d_in[1];
    const void* neut  = d_in[2];
    const void* assas = d_in[3];
    const void* vocab = d_in[4];
    const void* W1 = d_in[5];  const void* b1 = d_in[6];
    const void* W2 = d_in[7];  const void* b2 = d_in[8];
    const void* W3 = d_in[9];  const void* b3 = d_in[10];
    const void* W4 = d_in[11]; const void* b4 = d_in[12];
    float* out = (float*)d_out;

    // big mode: single-pass sims64 needs 64x100000 f32 sims buffer (~29 MB total ws)
    int big = ws_size >= (size_t)30 * 1024 * 1024;

    float* ws = (float*)d_ws;
    float* concat = ws;                             // 196608
    float* h1     = concat + 196608;                // 147456
    float* h2     = h1 + 147456;                    // 108800
    float* h3     = h2 + 108800;                    //  64000
    float* mo     = h3 + 64000;                     //  49152
    float* moT    = mo + 49152;                     //  49152 (big only)
    float* invn   = big ? (moT + 49152) : moT;      // 100000
    float* invemb = invn + 100000;                  //   1600
    float* simsPb = invemb + 1600;                  // 6400000 big / 3200000 small
    int* top_idx  = (int*)(simsPb + (big ? 6400000 : 3200000)); // 32768
    float* tot    = (float*)(top_idx + 64 * VK);    // 32768
    int* imax     = (int*)(tot + 64 * VK);          // 16384
    int* imin     = imax + 64 * KH;                 // 16384
    int* dflag    = imin + 64 * KH;                 // 1

    detect_kernel<<<1, 64, 0, stream>>>(vocab, dflag);

    prep_kernel<<<64, 256, 0, stream>>>(pos, neg, neut, assas, concat, invemb, dflag);

    // L1: 3072 -> 2304, tanh   (CH=384, KS=8)
    gemm_partial_kernel<<<dim3(36, 8), 256, 0, stream>>>(concat, W1, simsPb, 3072, 2304, 384, dflag);
    reduce_act_kernel<<<576, 256, 0, stream>>>(simsPb, b1, h1, 2304, 8, 1, dflag);
    // L2: 2304 -> 1700, tanh   (CH=256, KS=9)
    gemm_partial_kernel<<<dim3(27, 9), 256, 0, stream>>>(h1, W2, simsPb, 2304, 1700, 256, dflag);
    reduce_act_kernel<<<425, 256, 0, stream>>>(simsPb, b2, h2, 1700, 9, 1, dflag);
    // L3: 1700 -> 1000, tanh   (CH=192, KS=9)
    gemm_partial_kernel<<<dim3(16, 9), 256, 0, stream>>>(h2, W3, simsPb, 1700, 1000, 192, dflag);
    reduce_act_kernel<<<250, 256, 0, stream>>>(simsPb, b3, h3, 1000, 9, 1, dflag);
    // L4: 1000 -> 768, no act  (CH=128, KS=8)
    gemm_partial_kernel<<<dim3(12, 8), 256, 0, stream>>>(h3, W4, simsPb, 1000, 768, 128, dflag);
    reduce_act_kernel<<<192, 256, 0, stream>>>(simsPb, b4, mo, 768, 8, 0, dflag);

    norm_mo_kernel<<<64, 256, 0, stream>>>(mo, out, big ? moT : nullptr);

    if (big) {
        // single pass over vocab for all 64 rows; one select launch with 64 blocks
        sims64_kernel<<<1563, 256, 0, stream>>>(moT, vocab, simsPb, invn, dflag);
        select512_kernel<<<64, 1024, 0, stream>>>(simsPb, top_idx);
    } else {
        for (int pass = 0; pass < 2; pass++) {
            sims_kernel<<<1563, 256, 0, stream>>>(mo + (size_t)pass * 32 * D_, vocab,
                                                  simsPb, invn, pass == 0, dflag);
            select512_kernel<<<32, 1024, 0, stream>>>(simsPb, top_idx + (size_t)pass * 32 * VK);
        }
    }

    // one candidate per lane; 25 normalized embeddings staged in LDS per block
    tot_kernel<<<dim3(4, 64), 128, 0, stream>>>(top_idx, vocab, invn, invemb,
                                                pos, neg, neut, assas, tot, dflag);

    sort512_kernel<<<64, 256, 0, stream>>>(tot, imax, imin);

    pool_kernel<<<dim3(64, 2), 256, 0, stream>>>(top_idx, imax, imin, vocab, out, dflag);
}

// Round 4
// 1063.170 us; speedup vs baseline: 4.1222x; 1.0193x over previous
//
#include <hip/hip_runtime.h>
#include <hip/hip_bf16.h>
#include <stdint.h>

#define B_    64
#define D_    768
#define NVOC  100000
#define VK    512
#define KH    256
#define NPART 4
#define PLEN  25000

typedef __attribute__((ext_vector_type(8))) short short8v;   // 8 bf16 (4 VGPRs)
typedef __attribute__((ext_vector_type(4))) float f32x4;

__device__ __forceinline__ float b2f_raw(unsigned short u) {
    return __uint_as_float(((unsigned int)u) << 16);
}
// dtype-generic input load: isbf=1 -> bf16, else f32
__device__ __forceinline__ float ldin(const void* p, size_t i, int isbf) {
    return isbf ? b2f_raw(((const unsigned short*)p)[i]) : ((const float*)p)[i];
}
__device__ __forceinline__ float4 ldin4(const void* p, size_t i, int isbf) {
    if (isbf) {
        ushort4 r = *(const ushort4*)((const unsigned short*)p + i);
        return make_float4(b2f_raw(r.x), b2f_raw(r.y), b2f_raw(r.z), b2f_raw(r.w));
    }
    return *(const float4*)((const float*)p + i);
}
// round-to-nearest-even f32 -> bf16 bits
__device__ __forceinline__ unsigned short f2bf(float x) {
    uint32_t u = __float_as_uint(x);
    uint32_t r = (u + 0x7FFFu + ((u >> 16) & 1u)) >> 16;
    return (unsigned short)r;
}
// monotonic float->uint map (order-preserving)
__device__ __forceinline__ uint32_t fmono(float x) {
    uint32_t u = __float_as_uint(x);
    return u ^ (uint32_t)((((int32_t)u) >> 31) | 0x80000000u);
}

__device__ __forceinline__ float block_reduce_sum_256(float v, float* red) {
    int tid = threadIdx.x;
    red[tid] = v; __syncthreads();
    #pragma unroll
    for (int s = 128; s > 0; s >>= 1) {
        if (tid < s) red[tid] += red[tid + s];
        __syncthreads();
    }
    float r = red[0]; __syncthreads();
    return r;
}

// ---------------- dtype detector: f32 N(0,1) data vs bf16 data misread as f32 --------
__global__ void detect_kernel(const void* vocab, int* flag) {
    if (threadIdx.x == 0 && blockIdx.x == 0) {
        const float* vf = (const float*)vocab;
        int sane = 0;
        for (int i = 0; i < 256; i++) {
            float a = fabsf(vf[i]);
            if (a > 1e-4f && a < 64.0f) sane++;
        }
        *flag = (sane >= 200) ? 0 : 1;   // 0 = f32 inputs, 1 = bf16 inputs
    }
}

// ---------------- prep: pools into concat + per-embedding inverse norms ----------------
__global__ __launch_bounds__(256) void prep_kernel(
    const void* __restrict__ pos, const void* __restrict__ neg,
    const void* __restrict__ neut, const void* __restrict__ assas,
    float* __restrict__ concat, float* __restrict__ invemb,
    const int* __restrict__ dflag) {
    __shared__ float red[256];
    int isbf = *dflag;
    int b = blockIdx.x, tid = threadIdx.x;
    int d = tid * 3;
    const void* srcs[3] = {pos, neg, neut};
    const int cnts[3]  = {9, 8, 7};
    const int ieoff[3] = {0, 9, 17};
    const int coff[3]  = {2304, 0, 1536};
    for (int g = 0; g < 3; g++) {
        float m0 = 0.f, m1 = 0.f, m2 = 0.f;
        int cnt = cnts[g];
        for (int m = 0; m < cnt; m++) {
            size_t base = ((size_t)b * cnt + m) * D_ + d;
            float x0 = ldin(srcs[g], base + 0, isbf);
            float x1 = ldin(srcs[g], base + 1, isbf);
            float x2 = ldin(srcs[g], base + 2, isbf);
            float S = block_reduce_sum_256(x0 * x0 + x1 * x1 + x2 * x2, red);
            if (tid == 0)
                invemb[b * 25 + ieoff[g] + m] = 1.0f / fmaxf(sqrtf(S), 1e-12f);
            m0 += x0; m1 += x1; m2 += x2;
        }
        float invc = 1.0f / (float)cnt;
        m0 *= invc; m1 *= invc; m2 *= invc;
        float S = block_reduce_sum_256(m0 * m0 + m1 * m1 + m2 * m2, red);
        float inv = 1.0f / fmaxf(sqrtf(S), 1e-12f);
        float* o = concat + (size_t)b * 3072 + coff[g] + d;
        o[0] = m0 * inv; o[1] = m1 * inv; o[2] = m2 * inv;
    }
    size_t abase = (size_t)b * D_ + d;
    float x0 = ldin(assas, abase + 0, isbf);
    float x1 = ldin(assas, abase + 1, isbf);
    float x2 = ldin(assas, abase + 2, isbf);
    float* oc = concat + (size_t)b * 3072 + 768 + d;
    oc[0] = x0; oc[1] = x1; oc[2] = x2;
    float S = block_reduce_sum_256(x0 * x0 + x1 * x1 + x2 * x2, red);
    if (tid == 0) invemb[b * 25 + 24] = 1.0f / fmaxf(sqrtf(S), 1e-12f);
}

// ---------------- split-K GEMM partial: M=64, f32 X, generic W[K][N] ----------------
__global__ __launch_bounds__(256) void gemm_partial_kernel(
    const float* __restrict__ X, const void* __restrict__ W,
    float* __restrict__ P, int K, int N, int CH, const int* __restrict__ dflag) {
    __shared__ float xs[64][68];
    __shared__ float wt[64][68];
    int isbf = *dflag;
    int tid = threadIdx.x;
    int n0 = blockIdx.x * 64;
    int kstart = blockIdx.y * CH;
    int kend = min(K, kstart + CH);
    int tx = tid & 15, ty = tid >> 4;
    float acc[4][4] = {{0.f}};
    for (int k0 = kstart; k0 < kend; k0 += 64) {
        #pragma unroll
        for (int q = 0; q < 4; q++) {
            int e4 = tid + q * 256;
            int m = e4 >> 4, kk = (e4 & 15) * 4;
            float4 v = make_float4(0.f, 0.f, 0.f, 0.f);
            if (k0 + kk < kend) v = *(const float4*)(X + (size_t)m * K + k0 + kk);
            xs[kk + 0][m] = v.x; xs[kk + 1][m] = v.y;
            xs[kk + 2][m] = v.z; xs[kk + 3][m] = v.w;
        }
        #pragma unroll
        for (int q = 0; q < 4; q++) {
            int e4 = tid + q * 256;
            int kk = e4 >> 4, c = (e4 & 15) * 4;
            float4 v = make_float4(0.f, 0.f, 0.f, 0.f);
            if (k0 + kk < kend && n0 + c < N)
                v = ldin4(W, (size_t)(k0 + kk) * N + n0 + c, isbf);
            wt[kk][c + 0] = v.x; wt[kk][c + 1] = v.y;
            wt[kk][c + 2] = v.z; wt[kk][c + 3] = v.w;
        }
        __syncthreads();
        #pragma unroll 16
        for (int kk = 0; kk < 64; kk++) {
            float4 a = *(const float4*)&xs[kk][ty * 4];
            float4 w = *(const float4*)&wt[kk][tx * 4];
            acc[0][0] += a.x * w.x; acc[0][1] += a.x * w.y; acc[0][2] += a.x * w.z; acc[0][3] += a.x * w.w;
            acc[1][0] += a.y * w.x; acc[1][1] += a.y * w.y; acc[1][2] += a.y * w.z; acc[1][3] += a.y * w.w;
            acc[2][0] += a.z * w.x; acc[2][1] += a.z * w.y; acc[2][2] += a.z * w.z; acc[2][3] += a.z * w.w;
            acc[3][0] += a.w * w.x; acc[3][1] += a.w * w.y; acc[3][2] += a.w * w.z; acc[3][3] += a.w * w.w;
        }
        __syncthreads();
    }
    size_t base = (size_t)blockIdx.y * 64 * N;
    int n = n0 + tx * 4;
    if (n < N) {
        #pragma unroll
        for (int i = 0; i < 4; i++) {
            float4 o = make_float4(acc[i][0], acc[i][1], acc[i][2], acc[i][3]);
            *(float4*)(P + base + (size_t)(ty * 4 + i) * N + n) = o;
        }
    }
}

__global__ __launch_bounds__(256) void reduce_act_kernel(
    const float* __restrict__ P, const void* __restrict__ bias,
    float* __restrict__ Y, int N, int KS, int act, const int* __restrict__ dflag) {
    int isbf = *dflag;
    int idx = blockIdx.x * 256 + threadIdx.x;
    if (idx >= 64 * N) return;
    int n = idx % N;
    float s = 0.f;
    for (int ks = 0; ks < KS; ks++) s += P[(size_t)ks * 64 * N + idx];
    s += ldin(bias, n, isbf);
    if (act) s = tanhf(s);
    Y[idx] = s;
}

// normalize model_out rows in-place, emit to d_out, write moT (f32 path) and the
// MFMA A-fragment table moA (hi/lo bf16 split, pre-swizzled for 16x16x32 layout)
__global__ __launch_bounds__(256) void norm_mo_kernel(
    float* __restrict__ mo, float* __restrict__ out, float* __restrict__ moTp,
    unsigned short* __restrict__ moA) {
    __shared__ float red[256];
    int b = blockIdx.x, tid = threadIdx.x, d = tid * 3;
    float* r_ = mo + (size_t)b * D_ + d;
    float x0 = r_[0], x1 = r_[1], x2 = r_[2];
    float S = block_reduce_sum_256(x0 * x0 + x1 * x1 + x2 * x2, red);
    float inv = 1.0f / fmaxf(sqrtf(S), 1e-12f);
    x0 *= inv; x1 *= inv; x2 *= inv;
    r_[0] = x0; r_[1] = x1; r_[2] = x2;
    float* o = out + (size_t)b * D_ + d;
    o[0] = x0; o[1] = x1; o[2] = x2;
    if (moTp) {
        moTp[(size_t)(d + 0) * 64 + b] = x0;
        moTp[(size_t)(d + 1) * 64 + b] = x1;
        moTp[(size_t)(d + 2) * 64 + b] = x2;
    }
    if (moA) {
        float xv[3] = {x0, x1, x2};
        int w = b >> 4;
        #pragma unroll
        for (int c = 0; c < 3; c++) {
            int k = d + c;
            float x = xv[c];
            unsigned short hi = f2bf(x);
            unsigned short lo = f2bf(x - b2f_raw(hi));
            int kb2 = k >> 5, sub = (k >> 3) & 3, e = k & 7;
            int lane = (b & 15) | (sub << 4);
            // layout: (((hl*24 + kb2)*4 + w)*64 + lane)*8 + e
            moA[((((0 * 24 + kb2) * 4 + w) * 64) + lane) * 8 + e] = hi;
            moA[((((1 * 24 + kb2) * 4 + w) * 64) + lane) * 8 + e] = lo;
        }
    }
}

// ---------------- sims64 MFMA (bf16 inputs): 64 x 100000 x 768 in one vocab pass -----
// A = mo hi/lo (pre-swizzled moA), B = vocab (native bf16, exact).
// sims error <= ~2^-18 (hi/lo split), accum f32 in AGPRs.
__global__ __launch_bounds__(256) void sims64_mfma_kernel(
    const unsigned short* __restrict__ moA, const void* __restrict__ vocab,
    float* __restrict__ sims, float* __restrict__ invn,
    const int* __restrict__ dflag) {
    if (*dflag != 1) return;   // bf16 path only
    __shared__ unsigned short Bt[4096];   // [cc 0..7][row 0..63][e 0..7], 8 KB
    __shared__ float invLds[64];
    const unsigned short* voc = (const unsigned short*)vocab;
    int tid = threadIdx.x;
    int v0 = blockIdx.x * 64;
    int w = tid >> 6, lane = tid & 63;
    f32x4 acc[4];
    #pragma unroll
    for (int i = 0; i < 4; i++) acc[i] = (f32x4){0.f, 0.f, 0.f, 0.f};
    float ssqA = 0.f, ssqB = 0.f;
    int srow = tid >> 3;          // 0..31
    int scc  = tid & 7;           // 0..7
    for (int kb = 0; kb < 12; kb++) {
        // stage 64 rows x 64 k bf16 chunk-major; fold row-norm partial sums
        #pragma unroll
        for (int q = 0; q < 2; q++) {
            int row = srow + q * 32;
            uint4 r = make_uint4(0u, 0u, 0u, 0u);
            if (v0 + row < NVOC)
                r = *(const uint4*)(voc + (size_t)(v0 + row) * 768 + kb * 64 + scc * 8);
            float s = 0.f;
            uint32_t us[4] = {r.x, r.y, r.z, r.w};
            #pragma unroll
            for (int t2 = 0; t2 < 4; t2++) {
                float f0 = __uint_as_float(us[t2] << 16);
                float f1 = __uint_as_float(us[t2] & 0xFFFF0000u);
                s += f0 * f0 + f1 * f1;
            }
            if (q == 0) ssqA += s; else ssqB += s;
            *(uint4*)&Bt[(scc * 64 + row) * 8] = r;
        }
        __syncthreads();
        #pragma unroll
        for (int ks = 0; ks < 2; ks++) {
            int kb2 = kb * 2 + ks;
            short8v ah = *(const short8v*)&moA[((((0 * 24 + kb2) * 4 + w) * 64) + lane) * 8];
            short8v al = *(const short8v*)&moA[((((1 * 24 + kb2) * 4 + w) * 64) + lane) * 8];
            int cc = ks * 4 + (lane >> 4);
            #pragma unroll
            for (int vs = 0; vs < 4; vs++) {
                int row = vs * 16 + (lane & 15);
                short8v bf = *(const short8v*)&Bt[(cc * 64 + row) * 8];
                acc[vs] = __builtin_amdgcn_mfma_f32_16x16x32_bf16(ah, bf, acc[vs], 0, 0, 0);
                acc[vs] = __builtin_amdgcn_mfma_f32_16x16x32_bf16(al, bf, acc[vs], 0, 0, 0);
            }
        }
        __syncthreads();
    }
    // reduce ssq over the 8 cc-lanes of each row group (in-wave, lane = srow*8+scc)
    #pragma unroll
    for (int off = 1; off < 8; off <<= 1) {
        ssqA += __shfl_xor(ssqA, off, 64);
        ssqB += __shfl_xor(ssqB, off, 64);
    }
    if (scc == 0) {
        float iA = 1.0f / fmaxf(sqrtf(ssqA), 1e-12f);
        float iB = 1.0f / fmaxf(sqrtf(ssqB), 1e-12f);
        invLds[srow] = iA; invLds[srow + 32] = iB;
        if (v0 + srow < NVOC)      invn[v0 + srow] = iA;
        if (v0 + srow + 32 < NVOC) invn[v0 + srow + 32] = iB;
    }
    __syncthreads();
    // D: col = lane&15 (v-sub), row = (lane>>4)*4 + reg (m-sub within wave's 16)
    #pragma unroll
    for (int vs = 0; vs < 4; vs++) {
        int v = v0 + vs * 16 + (lane & 15);
        if (v < NVOC) {
            float iv = invLds[vs * 16 + (lane & 15)];
            #pragma unroll
            for (int reg = 0; reg < 4; reg++) {
                int m = w * 16 + (lane >> 4) * 4 + reg;
                sims[(size_t)m * NVOC + v] = acc[vs][reg] * iv;
            }
        }
    }
}

// ---------------- sims64 f32 fallback: ALL 64 rows x vocab^T in ONE vocab pass --------
__global__ __launch_bounds__(256) void sims64_kernel(
    const float* __restrict__ moT, const void* __restrict__ vocab,
    float* __restrict__ sims, float* __restrict__ invn,
    const int* __restrict__ dflag) {
    if (*dflag != 0) return;   // f32 path only
    __shared__ float xs[64 * 64];
    __shared__ float wt[64 * 64];
    int tid = threadIdx.x;
    int v0 = blockIdx.x * 64;
    int tx = tid & 15, ty = tid >> 4;
    float acc[4][4] = {{0.f}};
    float ssq[4] = {0.f, 0.f, 0.f, 0.f};
    for (int k0 = 0; k0 < 768; k0 += 64) {
        #pragma unroll
        for (int q = 0; q < 4; q++) {
            int e4 = tid + q * 256;
            int kr = e4 >> 4, m4 = (e4 & 15) * 4;
            float4 v = *(const float4*)(moT + (size_t)(k0 + kr) * 64 + m4);
            *(float4*)&xs[kr * 64 + m4] = v;
        }
        #pragma unroll
        for (int q = 0; q < 4; q++) {
            int e4 = tid + q * 256;
            int r = e4 >> 4, kq = e4 & 15, c = kq * 4;
            float4 v = make_float4(0.f, 0.f, 0.f, 0.f);
            if (v0 + r < NVOC)
                v = *(const float4*)((const float*)vocab + (size_t)(v0 + r) * 768 + k0 + c);
            int colp = r ^ ((kq & 7) << 2);
            wt[(c + 0) * 64 + colp] = v.x;
            wt[(c + 1) * 64 + colp] = v.y;
            wt[(c + 2) * 64 + colp] = v.z;
            wt[(c + 3) * 64 + colp] = v.w;
        }
        __syncthreads();
        #pragma unroll 16
        for (int kk = 0; kk < 64; kk++) {
            float4 a = *(const float4*)&xs[kk * 64 + ty * 4];
            float4 w = *(const float4*)&wt[kk * 64 + ((tx * 4) ^ (((kk >> 2) & 7) << 2))];
            ssq[0] += w.x * w.x; ssq[1] += w.y * w.y; ssq[2] += w.z * w.z; ssq[3] += w.w * w.w;
            acc[0][0] += a.x * w.x; acc[0][1] += a.x * w.y; acc[0][2] += a.x * w.z; acc[0][3] += a.x * w.w;
            acc[1][0] += a.y * w.x; acc[1][1] += a.y * w.y; acc[1][2] += a.y * w.z; acc[1][3] += a.y * w.w;
            acc[2][0] += a.z * w.x; acc[2][1] += a.z * w.y; acc[2][2] += a.z * w.z; acc[2][3] += a.z * w.w;
            acc[3][0] += a.w * w.x; acc[3][1] += a.w * w.y; acc[3][2] += a.w * w.z; acc[3][3] += a.w * w.w;
        }
        __syncthreads();
    }
    int v = v0 + tx * 4;
    if (v < NVOC) {
        float inv[4];
        #pragma unroll
        for (int j = 0; j < 4; j++) inv[j] = 1.0f / fmaxf(sqrtf(ssq[j]), 1e-12f);
        #pragma unroll
        for (int i = 0; i < 4; i++) {
            float4 o = make_float4(acc[i][0] * inv[0], acc[i][1] * inv[1],
                                   acc[i][2] * inv[2], acc[i][3] * inv[3]);
            *(float4*)(sims + (size_t)(ty * 4 + i) * NVOC + v) = o;
        }
        if (ty == 0) *(float4*)(invn + v) = make_float4(inv[0], inv[1], inv[2], inv[3]);
    }
}

// ---------------- sims (small-ws fallback 2-pass, 32 rows) ---------------------------
__global__ __launch_bounds__(256) void sims_kernel(
    const float* __restrict__ mo32, const void* __restrict__ vocab,
    float* __restrict__ sims, float* __restrict__ invn, int winv,
    const int* __restrict__ dflag) {
    __shared__ float xs[64][36];
    __shared__ float wt[64][68];
    int isbf = *dflag;
    int tid = threadIdx.x;
    int v0 = blockIdx.x * 64;
    int tx = tid & 15, ty = tid >> 4;
    float acc[2][4] = {{0.f}};
    float ssq[4] = {0.f, 0.f, 0.f, 0.f};
    for (int k0 = 0; k0 < 768; k0 += 64) {
        #pragma unroll
        for (int q = 0; q < 2; q++) {
            int e4 = tid + q * 256;
            int m = e4 >> 4, kk = (e4 & 15) * 4;
            float4 v = *(const float4*)(mo32 + (size_t)m * 768 + k0 + kk);
            xs[kk + 0][m] = v.x; xs[kk + 1][m] = v.y;
            xs[kk + 2][m] = v.z; xs[kk + 3][m] = v.w;
        }
        #pragma unroll
        for (int q = 0; q < 4; q++) {
            int e4 = tid + q * 256;
            int r = e4 >> 4, c = (e4 & 15) * 4;
            float4 v = make_float4(0.f, 0.f, 0.f, 0.f);
            if (v0 + r < NVOC)
                v = ldin4(vocab, (size_t)(v0 + r) * 768 + k0 + c, isbf);
            wt[c + 0][r] = v.x; wt[c + 1][r] = v.y;
            wt[c + 2][r] = v.z; wt[c + 3][r] = v.w;
        }
        __syncthreads();
        #pragma unroll 16
        for (int kk = 0; kk < 64; kk++) {
            float2 a = *(const float2*)&xs[kk][ty * 2];
            float4 w = *(const float4*)&wt[kk][tx * 4];
            ssq[0] += w.x * w.x; ssq[1] += w.y * w.y; ssq[2] += w.z * w.z; ssq[3] += w.w * w.w;
            acc[0][0] += a.x * w.x; acc[0][1] += a.x * w.y; acc[0][2] += a.x * w.z; acc[0][3] += a.x * w.w;
            acc[1][0] += a.y * w.x; acc[1][1] += a.y * w.y; acc[1][2] += a.y * w.z; acc[1][3] += a.y * w.w;
        }
        __syncthreads();
    }
    int v = v0 + tx * 4;
    if (v < NVOC) {
        float inv[4];
        #pragma unroll
        for (int j = 0; j < 4; j++) inv[j] = 1.0f / fmaxf(sqrtf(ssq[j]), 1e-12f);
        #pragma unroll
        for (int i = 0; i < 2; i++) {
            float4 o = make_float4(acc[i][0] * inv[0], acc[i][1] * inv[1],
                                   acc[i][2] * inv[2], acc[i][3] * inv[3]);
            *(float4*)(sims + (size_t)(ty * 2 + i) * NVOC + v) = o;
        }
        if (ty == 0 && winv) *(float4*)(invn + v) = make_float4(inv[0], inv[1], inv[2], inv[3]);
    }
}

// ---------------- bitonic sort desc on u64 keys ----------------
__device__ void bitonic_desc_u64(unsigned long long* d, int n, int tid, int nt) {
    for (int k = 2; k <= n; k <<= 1) {
        for (int j = k >> 1; j > 0; j >>= 1) {
            for (int i = tid; i < n; i += nt) {
                int ixj = i ^ j;
                if (ixj > i) {
                    unsigned long long a = d[i], b = d[ixj];
                    bool up = ((i & k) == 0);
                    if (up ? (a < b) : (a > b)) { d[i] = b; d[ixj] = a; }
                }
            }
            __syncthreads();
        }
    }
}

// ---------------- partitioned exact top-512 (jax.lax.top_k semantics) ----------------
// Each (b, part) block: top-512 keys of its 25000-slice, fully sorted.
// Keys (fmono<<32)|~v are globally comparable -> partition top-512s form an exact
// superset of the row's global top-512.
__global__ __launch_bounds__(1024) void pselect_kernel(
    const float* __restrict__ sims, unsigned long long* __restrict__ psel) {
    __shared__ int hist[4096];
    __shared__ unsigned long long cand[2048];
    __shared__ int ssum[1024];
    __shared__ int s_Tg, s_T, s_cnt;
    int b = blockIdx.y, part = blockIdx.x, tid = threadIdx.x;
    const float* row = sims + (size_t)b * NVOC + (size_t)part * PLEN;
    #pragma unroll
    for (int q = 0; q < 4; q++) hist[tid * 4 + q] = 0;
    __syncthreads();
    for (int v = tid; v < PLEN; v += 1024) {
        uint32_t u = fmono(row[v]);
        atomicAdd(&hist[u >> 20], 1);
    }
    __syncthreads();
    int a_ = 0;
    #pragma unroll
    for (int q = 0; q < 4; q++) a_ += hist[tid * 4 + q];
    ssum[tid] = a_; __syncthreads();
    for (int off = 1; off < 1024; off <<= 1) {
        int add = (tid + off < 1024) ? ssum[tid + off] : 0;
        __syncthreads();
        ssum[tid] += add;
        __syncthreads();
    }
    if (ssum[tid] >= VK && (tid == 1023 || ssum[tid + 1] < VK)) s_Tg = tid;
    __syncthreads();
    if (tid == 0) {
        int g = s_Tg;
        int above = (g == 1023) ? 0 : ssum[g + 1];
        int T = g * 4;
        for (int bin = g * 4 + 3; bin >= g * 4; bin--) {
            int c = hist[bin];
            if (above + c >= VK) { T = bin; break; }
            above += c;
        }
        s_T = T; s_cnt = 0;
    }
    __syncthreads();
    uint32_t T = (uint32_t)s_T;
    for (int v = tid; v < PLEN; v += 1024) {
        uint32_t u = fmono(row[v]);
        if ((u >> 20) >= T) {
            int p = atomicAdd(&s_cnt, 1);
            if (p < 2048) {
                uint32_t vg = (uint32_t)(part * PLEN + v);
                cand[p] = ((unsigned long long)u << 32) | (uint32_t)(~vg);
            }
        }
    }
    __syncthreads();
    int total = min(s_cnt, 2048);
    for (int i = tid; i < 2048; i += 1024)
        if (i >= total) cand[i] = 0ull;
    __syncthreads();
    bitonic_desc_u64(cand, 2048, tid, 1024);
    if (tid < VK) psel[((size_t)b * NPART + part) * VK + tid] = cand[tid];
}

__global__ __launch_bounds__(512) void pmerge_kernel(
    const unsigned long long* __restrict__ psel, int* __restrict__ top_idx) {
    __shared__ unsigned long long key[2048];
    int b = blockIdx.x, tid = threadIdx.x;
    for (int i = tid; i < 2048; i += 512) key[i] = psel[(size_t)b * 2048 + i];
    __syncthreads();
    bitonic_desc_u64(key, 2048, tid, 512);
    if (tid < VK) top_idx[(size_t)b * VK + tid] = (int)(~(uint32_t)(key[tid] & 0xFFFFFFFFull));
}

// ---------------- small-ws fallback: full-row top-512 ----------------
__global__ __launch_bounds__(1024) void select512_kernel(
    const float* __restrict__ sims, int* __restrict__ top_idx) {
    __shared__ int hist[4096];
    __shared__ unsigned long long cand[4096];
    __shared__ int ssum[1024];
    __shared__ int s_Tg, s_T, s_cnt;
    int b = blockIdx.x, tid = threadIdx.x;
    const float* row = sims + (size_t)b * NVOC;
    #pragma unroll
    for (int q = 0; q < 4; q++) hist[tid * 4 + q] = 0;
    __syncthreads();
    for (int v = tid; v < NVOC; v += 1024) {
        uint32_t u = fmono(row[v]);
        atomicAdd(&hist[u >> 20], 1);
    }
    __syncthreads();
    int a_ = 0;
    #pragma unroll
    for (int q = 0; q < 4; q++) a_ += hist[tid * 4 + q];
    ssum[tid] = a_; __syncthreads();
    for (int off = 1; off < 1024; off <<= 1) {
        int add = (tid + off < 1024) ? ssum[tid + off] : 0;
        __syncthreads();
        ssum[tid] += add;
        __syncthreads();
    }
    if (ssum[tid] >= VK && (tid == 1023 || ssum[tid + 1] < VK)) s_Tg = tid;
    __syncthreads();
    if (tid == 0) {
        int g = s_Tg;
        int above = (g == 1023) ? 0 : ssum[g + 1];
        int T = g * 4;
        for (int bin = g * 4 + 3; bin >= g * 4; bin--) {
            int c = hist[bin];
            if (above + c >= VK) { T = bin; break; }
            above += c;
        }
        s_T = T; s_cnt = 0;
    }
    __syncthreads();
    uint32_t T = (uint32_t)s_T;
    for (int v = tid; v < NVOC; v += 1024) {
        uint32_t u = fmono(row[v]);
        if ((u >> 20) >= T) {
            int p = atomicAdd(&s_cnt, 1);
            if (p < 4096) cand[p] = ((unsigned long long)u << 32) | (uint32_t)(~v);
        }
    }
    __syncthreads();
    int total = min(s_cnt, 4096);
    for (int i = tid; i < 4096; i += 1024)
        if (i >= total) cand[i] = 0ull;
    __syncthreads();
    bitonic_desc_u64(cand, 4096, tid, 1024);
    if (tid < VK) top_idx[(size_t)b * VK + tid] = (int)(~(uint32_t)(cand[tid] & 0xFFFFFFFFull));
}

// ---------------- per-candidate 25 sims -> primary/secondary -> tot_reward ------------
__global__ __launch_bounds__(128) void tot_kernel(
    const int* __restrict__ top_idx, const void* __restrict__ vocab,
    const float* __restrict__ invn, const float* __restrict__ invemb,
    const void* __restrict__ pos, const void* __restrict__ neg,
    const void* __restrict__ neut, const void* __restrict__ assas,
    float* __restrict__ tot, const int* __restrict__ dflag) {
    __shared__ float E[25 * 384];
    int isbf = *dflag;
    int b = blockIdx.y;
    int j = blockIdx.x * 128 + threadIdx.x;
    int v = top_idx[(size_t)b * VK + j];
    if ((unsigned)v >= (unsigned)NVOC) v = 0;
    size_t vbase = (size_t)v * D_;
    float p[25];
    #pragma unroll
    for (int i = 0; i < 25; i++) p[i] = 0.f;

    for (int h = 0; h < 2; h++) {
        __syncthreads();
        for (int u = threadIdx.x; u < 2400; u += 128) {
            int i = u / 96;
            int c = (u - i * 96) * 4;
            const void* ep; size_t eb;
            if (i < 9)       { ep = pos;   eb = ((size_t)b * 9 + i) * D_; }
            else if (i < 17) { ep = neg;   eb = ((size_t)b * 8 + (i - 9)) * D_; }
            else if (i < 24) { ep = neut;  eb = ((size_t)b * 7 + (i - 17)) * D_; }
            else             { ep = assas; eb = (size_t)b * D_; }
            float4 x = ldin4(ep, eb + h * 384 + c, isbf);
            float s = invemb[b * 25 + i];
            E[i * 384 + c + 0] = x.x * s;
            E[i * 384 + c + 1] = x.y * s;
            E[i * 384 + c + 2] = x.z * s;
            E[i * 384 + c + 3] = x.w * s;
        }
        __syncthreads();
        for (int c = 0; c < 384; c += 4) {
            float4 w = ldin4(vocab, vbase + h * 384 + c, isbf);
            #pragma unroll
            for (int i = 0; i < 25; i++) {
                float4 e = *(const float4*)&E[i * 384 + c];
                p[i] += w.x * e.x + w.y * e.y + w.z * e.z + w.w * e.w;
            }
        }
    }

    float invv = invn[v];
    #pragma unroll
    for (int i = 0; i < 25; i++) p[i] *= invv;
    float mx = -1e30f; int am = 9;
    #pragma unroll
    for (int i = 9; i < 25; i++) if (p[i] > mx) { mx = p[i]; am = i; }
    int primary = 0;
    #pragma unroll
    for (int i = 0; i < 9; i++) primary += (p[i] >= mx) ? 1 : 0;
    float secondary = (am == 24) ? -10.0f : ((am >= 17) ? 1.0f : 0.0f);
    tot[(size_t)b * VK + j] = (float)primary + secondary;
}

// ---------------- top/bottom 256 of tot (exact tie semantics) ----------------
__global__ __launch_bounds__(256) void sort512_kernel(
    const float* __restrict__ tot, int* __restrict__ idx_max, int* __restrict__ idx_min) {
    __shared__ unsigned long long key[512];
    int b = blockIdx.x, tid = threadIdx.x;
    for (int pass = 0; pass < 2; pass++) {
        for (int j = tid; j < 512; j += 256) {
            uint32_t m = fmono(tot[(size_t)b * VK + j]);
            if (pass) m = ~m;
            key[j] = ((unsigned long long)m << 32) | (uint32_t)(511 - j);
        }
        __syncthreads();
        bitonic_desc_u64(key, 512, tid, 256);
        int* dst = pass ? idx_min : idx_max;
        if (tid < 256) dst[(size_t)b * KH + tid] = 511 - (int)(key[tid] & 0xFFFFFFFFull);
        __syncthreads();
    }
}

// ---------------- gather + mean + normalize; search_embedding bit-exact copy ----------
__global__ __launch_bounds__(256) void pool_kernel(
    const int* __restrict__ top_idx, const int* __restrict__ idx_max,
    const int* __restrict__ idx_min, const void* __restrict__ vocab,
    float* __restrict__ out, const int* __restrict__ dflag) {
    __shared__ float red[256];
    int isbf = *dflag;
    int b = blockIdx.x, s = blockIdx.y, tid = threadIdx.x;
    const int* sel = s ? idx_min : idx_max;
    int d = tid * 3;
    float a0 = 0.f, a1 = 0.f, a2 = 0.f;
    for (int r = 0; r < 256; r++) {
        int v = top_idx[(size_t)b * VK + sel[(size_t)b * KH + r]];
        if ((unsigned)v >= (unsigned)NVOC) v = 0;
        size_t vb = (size_t)v * D_ + d;
        a0 += ldin(vocab, vb + 0, isbf);
        a1 += ldin(vocab, vb + 1, isbf);
        a2 += ldin(vocab, vb + 2, isbf);
    }
    a0 *= (1.0f / 256.0f); a1 *= (1.0f / 256.0f); a2 *= (1.0f / 256.0f);
    float S = block_reduce_sum_256(a0 * a0 + a1 * a1 + a2 * a2, red);
    float inv = 1.0f / fmaxf(sqrtf(S), 1e-12f);
    float* o = out + (size_t)(2 + s) * (B_ * D_) + (size_t)b * D_ + d;
    o[0] = a0 * inv;
    o[1] = a1 * inv;
    o[2] = a2 * inv;
    if (s == 0) {
        int v0 = top_idx[(size_t)b * VK + sel[(size_t)b * KH + 0]];
        if ((unsigned)v0 >= (unsigned)NVOC) v0 = 0;
        size_t vb = (size_t)v0 * D_ + d;
        float* so = out + (size_t)(B_ * D_) + (size_t)b * D_ + d;
        so[0] = ldin(vocab, vb + 0, isbf);
        so[1] = ldin(vocab, vb + 1, isbf);
        so[2] = ldin(vocab, vb + 2, isbf);
    }
}

extern "C" void kernel_launch(void* const* d_in, const int* in_sizes, int n_in,
                              void* d_out, int out_size, void* d_ws, size_t ws_size,
                              hipStream_t stream) {
    const void* pos   = d_in[0];
    const void* neg   = d_in[1];
    const void* neut  = d_in[2];
    const void* assas = d_in[3];
    const void* vocab = d_in[4];
    const void* W1 = d_in[5];  const void* b1 = d_in[6];
    const void* W2 = d_in[7];  const void* b2 = d_in[8];
    const void* W3 = d_in[9];  const void* b3 = d_in[10];
    const void* W4 = d_in[11]; const void* b4 = d_in[12];
    float* out = (float*)d_out;

    int big = ws_size >= (size_t)32 * 1024 * 1024;

    float* ws = (float*)d_ws;
    if (big) {
        float* concat = ws;                              // 196608
        float* h1     = concat + 196608;                 // 147456
        float* h2     = h1 + 147456;                     // 108800
        float* h3     = h2 + 108800;                     //  64000
        float* mo     = h3 + 64000;                      //  49152
        float* moT    = mo + 49152;                      //  49152
        float* moA_f  = moT + 49152;                     //  49152 (98304 bf16)
        float* invn   = moA_f + 49152;                   // 100000
        float* invemb = invn + 100000;                   //   1600
        float* simsPb = invemb + 1600;                   // 6400000
        int* top_idx  = (int*)(simsPb + 6400000);        // 32768
        float* tot    = (float*)(top_idx + 64 * VK);     // 32768
        int* imax     = (int*)(tot + 64 * VK);           // 16384
        int* imin     = imax + 64 * KH;                  // 16384
        unsigned long long* psel = (unsigned long long*)(imin + 64 * KH); // 131072 u64
        int* dflag    = (int*)(psel + 64 * NPART * VK);  // 1
        unsigned short* moAu = (unsigned short*)moA_f;

        detect_kernel<<<1, 64, 0, stream>>>(vocab, dflag);
        prep_kernel<<<64, 256, 0, stream>>>(pos, neg, neut, assas, concat, invemb, dflag);

        gemm_partial_kernel<<<dim3(36, 8), 256, 0, stream>>>(concat, W1, simsPb, 3072, 2304, 384, dflag);
        reduce_act_kernel<<<576, 256, 0, stream>>>(simsPb, b1, h1, 2304, 8, 1, dflag);
        gemm_partial_kernel<<<dim3(27, 9), 256, 0, stream>>>(h1, W2, simsPb, 2304, 1700, 256, dflag);
        reduce_act_kernel<<<425, 256, 0, stream>>>(simsPb, b2, h2, 1700, 9, 1, dflag);
        gemm_partial_kernel<<<dim3(16, 9), 256, 0, stream>>>(h2, W3, simsPb, 1700, 1000, 192, dflag);
        reduce_act_kernel<<<250, 256, 0, stream>>>(simsPb, b3, h3, 1000, 9, 1, dflag);
        gemm_partial_kernel<<<dim3(12, 8), 256, 0, stream>>>(h3, W4, simsPb, 1000, 768, 128, dflag);
        reduce_act_kernel<<<192, 256, 0, stream>>>(simsPb, b4, mo, 768, 8, 0, dflag);

        norm_mo_kernel<<<64, 256, 0, stream>>>(mo, out, moT, moAu);

        // dtype-gated pair: exactly one does the work, the other retires immediately
        sims64_mfma_kernel<<<1563, 256, 0, stream>>>(moAu, vocab, simsPb, invn, dflag);
        sims64_kernel<<<1563, 256, 0, stream>>>(moT, vocab, simsPb, invn, dflag);

        pselect_kernel<<<dim3(NPART, 64), 1024, 0, stream>>>(simsPb, psel);
        pmerge_kernel<<<64, 512, 0, stream>>>(psel, top_idx);

        tot_kernel<<<dim3(4, 64), 128, 0, stream>>>(top_idx, vocab, invn, invemb,
                                                    pos, neg, neut, assas, tot, dflag);
        sort512_kernel<<<64, 256, 0, stream>>>(tot, imax, imin);
        pool_kernel<<<dim3(64, 2), 256, 0, stream>>>(top_idx, imax, imin, vocab, out, dflag);
    } else {
        float* concat = ws;                              // 196608
        float* h1     = concat + 196608;                 // 147456
        float* h2     = h1 + 147456;                     // 108800
        float* h3     = h2 + 108800;                     //  64000
        float* mo     = h3 + 64000;                      //  49152
        float* invn   = mo + 49152;                      // 100000
        float* invemb = invn + 100000;                   //   1600
        float* simsPb = invemb + 1600;                   // 3200000
        int* top_idx  = (int*)(simsPb + 3200000);        // 32768
        float* tot    = (float*)(top_idx + 64 * VK);     // 32768
        int* imax     = (int*)(tot + 64 * VK);           // 16384
        int* imin     = imax + 64 * KH;                  // 16384
        int* dflag    = imin + 64 * KH;                  // 1

        detect_kernel<<<1, 64, 0, stream>>>(vocab, dflag);
        prep_kernel<<<64, 256, 0, stream>>>(pos, neg, neut, assas, concat, invemb, dflag);

        gemm_partial_kernel<<<dim3(36, 8), 256, 0, stream>>>(concat, W1, simsPb, 3072, 2304, 384, dflag);
        reduce_act_kernel<<<576, 256, 0, stream>>>(simsPb, b1, h1, 2304, 8, 1, dflag);
        gemm_partial_kernel<<<dim3(27, 9), 256, 0, stream>>>(h1, W2, simsPb, 2304, 1700, 256, dflag);
        reduce_act_kernel<<<425, 256, 0, stream>>>(simsPb, b2, h2, 1700, 9, 1, dflag);
        gemm_partial_kernel<<<dim3(16, 9), 256, 0, stream>>>(h2, W3, simsPb, 1700, 1000, 192, dflag);
        reduce_act_kernel<<<250, 256, 0, stream>>>(simsPb, b3, h3, 1000, 9, 1, dflag);
        gemm_partial_kernel<<<dim3(12, 8), 256, 0, stream>>>(h3, W4, simsPb, 1000, 768, 128, dflag);
        reduce_act_kernel<<<192, 256, 0, stream>>>(simsPb, b4, mo, 768, 8, 0, dflag);

        norm_mo_kernel<<<64, 256, 0, stream>>>(mo, out, nullptr, nullptr);

        for (int pass = 0; pass < 2; pass++) {
            sims_kernel<<<1563, 256, 0, stream>>>(mo + (size_t)pass * 32 * D_, vocab,
                                                  simsPb, invn, pass == 0, dflag);
            select512_kernel<<<32, 1024, 0, stream>>>(simsPb, top_idx + (size_t)pass * 32 * VK);
        }

        tot_kernel<<<dim3(4, 64), 128, 0, stream>>>(top_idx, vocab, invn, invemb,
                                                    pos, neg, neut, assas, tot, dflag);
        sort512_kernel<<<64, 256, 0, stream>>>(tot, imax, imin);
        pool_kernel<<<dim3(64, 2), 256, 0, stream>>>(top_idx, imax, imin, vocab, out, dflag);
    }
}

// Round 7
// 999.019 us; speedup vs baseline: 4.3869x; 1.0642x over previous
//
#include <hip/hip_runtime.h>
#include <hip/hip_bf16.h>
#include <stdint.h>

#define B_    64
#define D_    768
#define NVOC  100000
#define VK    512
#define KH    256
#define NPART 4
#define PLEN  25000

typedef __attribute__((ext_vector_type(8))) short short8v;   // 8 bf16 (4 VGPRs)
typedef __attribute__((ext_vector_type(4))) float f32x4;

__device__ __forceinline__ float b2f_raw(unsigned short u) {
    return __uint_as_float(((unsigned int)u) << 16);
}
// dtype-generic input load: isbf=1 -> bf16, else f32
__device__ __forceinline__ float ldin(const void* p, size_t i, int isbf) {
    return isbf ? b2f_raw(((const unsigned short*)p)[i]) : ((const float*)p)[i];
}
__device__ __forceinline__ float4 ldin4(const void* p, size_t i, int isbf) {
    if (isbf) {
        ushort4 r = *(const ushort4*)((const unsigned short*)p + i);
        return make_float4(b2f_raw(r.x), b2f_raw(r.y), b2f_raw(r.z), b2f_raw(r.w));
    }
    return *(const float4*)((const float*)p + i);
}
// round-to-nearest-even f32 -> bf16 bits
__device__ __forceinline__ unsigned short f2bf(float x) {
    uint32_t u = __float_as_uint(x);
    uint32_t r = (u + 0x7FFFu + ((u >> 16) & 1u)) >> 16;
    return (unsigned short)r;
}
// monotonic float->uint map (order-preserving)
__device__ __forceinline__ uint32_t fmono(float x) {
    uint32_t u = __float_as_uint(x);
    return u ^ (uint32_t)((((int32_t)u) >> 31) | 0x80000000u);
}

__device__ __forceinline__ float block_reduce_sum_256(float v, float* red) {
    int tid = threadIdx.x;
    red[tid] = v; __syncthreads();
    #pragma unroll
    for (int s = 128; s > 0; s >>= 1) {
        if (tid < s) red[tid] += red[tid + s];
        __syncthreads();
    }
    float r = red[0]; __syncthreads();
    return r;
}

// ---------------- dtype detector: f32 N(0,1) data vs bf16 data misread as f32 --------
__global__ void detect_kernel(const void* vocab, int* flag) {
    if (threadIdx.x == 0 && blockIdx.x == 0) {
        const float* vf = (const float*)vocab;
        int sane = 0;
        for (int i = 0; i < 256; i++) {
            float a = fabsf(vf[i]);
            if (a > 1e-4f && a < 64.0f) sane++;
        }
        *flag = (sane >= 200) ? 0 : 1;   // 0 = f32 inputs, 1 = bf16 inputs
    }
}

// ---------------- prep: pools into concat + per-embedding inverse norms ----------------
__global__ __launch_bounds__(256) void prep_kernel(
    const void* __restrict__ pos, const void* __restrict__ neg,
    const void* __restrict__ neut, const void* __restrict__ assas,
    float* __restrict__ concat, float* __restrict__ invemb,
    const int* __restrict__ dflag) {
    __shared__ float red[256];
    int isbf = *dflag;
    int b = blockIdx.x, tid = threadIdx.x;
    int d = tid * 3;
    const void* srcs[3] = {pos, neg, neut};
    const int cnts[3]  = {9, 8, 7};
    const int ieoff[3] = {0, 9, 17};
    const int coff[3]  = {2304, 0, 1536};
    for (int g = 0; g < 3; g++) {
        float m0 = 0.f, m1 = 0.f, m2 = 0.f;
        int cnt = cnts[g];
        for (int m = 0; m < cnt; m++) {
            size_t base = ((size_t)b * cnt + m) * D_ + d;
            float x0 = ldin(srcs[g], base + 0, isbf);
            float x1 = ldin(srcs[g], base + 1, isbf);
            float x2 = ldin(srcs[g], base + 2, isbf);
            float S = block_reduce_sum_256(x0 * x0 + x1 * x1 + x2 * x2, red);
            if (tid == 0)
                invemb[b * 25 + ieoff[g] + m] = 1.0f / fmaxf(sqrtf(S), 1e-12f);
            m0 += x0; m1 += x1; m2 += x2;
        }
        float invc = 1.0f / (float)cnt;
        m0 *= invc; m1 *= invc; m2 *= invc;
        float S = block_reduce_sum_256(m0 * m0 + m1 * m1 + m2 * m2, red);
        float inv = 1.0f / fmaxf(sqrtf(S), 1e-12f);
        float* o = concat + (size_t)b * 3072 + coff[g] + d;
        o[0] = m0 * inv; o[1] = m1 * inv; o[2] = m2 * inv;
    }
    size_t abase = (size_t)b * D_ + d;
    float x0 = ldin(assas, abase + 0, isbf);
    float x1 = ldin(assas, abase + 1, isbf);
    float x2 = ldin(assas, abase + 2, isbf);
    float* oc = concat + (size_t)b * 3072 + 768 + d;
    oc[0] = x0; oc[1] = x1; oc[2] = x2;
    float S = block_reduce_sum_256(x0 * x0 + x1 * x1 + x2 * x2, red);
    if (tid == 0) invemb[b * 25 + 24] = 1.0f / fmaxf(sqrtf(S), 1e-12f);
}

// ---------------- split-K GEMM partial: M=64, f32 X, generic W[K][N] ----------------
__global__ __launch_bounds__(256) void gemm_partial_kernel(
    const float* __restrict__ X, const void* __restrict__ W,
    float* __restrict__ P, int K, int N, int CH, const int* __restrict__ dflag) {
    __shared__ float xs[64][68];
    __shared__ float wt[64][68];
    int isbf = *dflag;
    int tid = threadIdx.x;
    int n0 = blockIdx.x * 64;
    int kstart = blockIdx.y * CH;
    int kend = min(K, kstart + CH);
    int tx = tid & 15, ty = tid >> 4;
    float acc[4][4] = {{0.f}};
    for (int k0 = kstart; k0 < kend; k0 += 64) {
        #pragma unroll
        for (int q = 0; q < 4; q++) {
            int e4 = tid + q * 256;
            int m = e4 >> 4, kk = (e4 & 15) * 4;
            float4 v = make_float4(0.f, 0.f, 0.f, 0.f);
            if (k0 + kk < kend) v = *(const float4*)(X + (size_t)m * K + k0 + kk);
            xs[kk + 0][m] = v.x; xs[kk + 1][m] = v.y;
            xs[kk + 2][m] = v.z; xs[kk + 3][m] = v.w;
        }
        #pragma unroll
        for (int q = 0; q < 4; q++) {
            int e4 = tid + q * 256;
            int kk = e4 >> 4, c = (e4 & 15) * 4;
            float4 v = make_float4(0.f, 0.f, 0.f, 0.f);
            if (k0 + kk < kend && n0 + c < N)
                v = ldin4(W, (size_t)(k0 + kk) * N + n0 + c, isbf);
            wt[kk][c + 0] = v.x; wt[kk][c + 1] = v.y;
            wt[kk][c + 2] = v.z; wt[kk][c + 3] = v.w;
        }
        __syncthreads();
        #pragma unroll 16
        for (int kk = 0; kk < 64; kk++) {
            float4 a = *(const float4*)&xs[kk][ty * 4];
            float4 w = *(const float4*)&wt[kk][tx * 4];
            acc[0][0] += a.x * w.x; acc[0][1] += a.x * w.y; acc[0][2] += a.x * w.z; acc[0][3] += a.x * w.w;
            acc[1][0] += a.y * w.x; acc[1][1] += a.y * w.y; acc[1][2] += a.y * w.z; acc[1][3] += a.y * w.w;
            acc[2][0] += a.z * w.x; acc[2][1] += a.z * w.y; acc[2][2] += a.z * w.z; acc[2][3] += a.z * w.w;
            acc[3][0] += a.w * w.x; acc[3][1] += a.w * w.y; acc[3][2] += a.w * w.z; acc[3][3] += a.w * w.w;
        }
        __syncthreads();
    }
    size_t base = (size_t)blockIdx.y * 64 * N;
    int n = n0 + tx * 4;
    if (n < N) {
        #pragma unroll
        for (int i = 0; i < 4; i++) {
            float4 o = make_float4(acc[i][0], acc[i][1], acc[i][2], acc[i][3]);
            *(float4*)(P + base + (size_t)(ty * 4 + i) * N + n) = o;
        }
    }
}

__global__ __launch_bounds__(256) void reduce_act_kernel(
    const float* __restrict__ P, const void* __restrict__ bias,
    float* __restrict__ Y, int N, int KS, int act, const int* __restrict__ dflag) {
    int isbf = *dflag;
    int idx = blockIdx.x * 256 + threadIdx.x;
    if (idx >= 64 * N) return;
    int n = idx % N;
    float s = 0.f;
    for (int ks = 0; ks < KS; ks++) s += P[(size_t)ks * 64 * N + idx];
    s += ldin(bias, n, isbf);
    if (act) s = tanhf(s);
    Y[idx] = s;
}

// normalize model_out rows in-place, emit to d_out, write moT (unused spare) and the
// MFMA A-fragment table moA (hi/lo bf16 split, pre-swizzled for 16x16x32 layout)
__global__ __launch_bounds__(256) void norm_mo_kernel(
    float* __restrict__ mo, float* __restrict__ out, float* __restrict__ moTp,
    unsigned short* __restrict__ moA) {
    __shared__ float red[256];
    int b = blockIdx.x, tid = threadIdx.x, d = tid * 3;
    float* r_ = mo + (size_t)b * D_ + d;
    float x0 = r_[0], x1 = r_[1], x2 = r_[2];
    float S = block_reduce_sum_256(x0 * x0 + x1 * x1 + x2 * x2, red);
    float inv = 1.0f / fmaxf(sqrtf(S), 1e-12f);
    x0 *= inv; x1 *= inv; x2 *= inv;
    r_[0] = x0; r_[1] = x1; r_[2] = x2;
    float* o = out + (size_t)b * D_ + d;
    o[0] = x0; o[1] = x1; o[2] = x2;
    if (moTp) {
        moTp[(size_t)(d + 0) * 64 + b] = x0;
        moTp[(size_t)(d + 1) * 64 + b] = x1;
        moTp[(size_t)(d + 2) * 64 + b] = x2;
    }
    if (moA) {
        float xv[3] = {x0, x1, x2};
        int w = b >> 4;
        #pragma unroll
        for (int c = 0; c < 3; c++) {
            int k = d + c;
            float x = xv[c];
            unsigned short hi = f2bf(x);
            unsigned short lo = f2bf(x - b2f_raw(hi));
            int kb2 = k >> 5, sub = (k >> 3) & 3, e = k & 7;
            int lane = (b & 15) | (sub << 4);
            // layout: (((hl*24 + kb2)*4 + w)*64 + lane)*8 + e
            moA[((((0 * 24 + kb2) * 4 + w) * 64) + lane) * 8 + e] = hi;
            moA[((((1 * 24 + kb2) * 4 + w) * 64) + lane) * 8 + e] = lo;
        }
    }
}

// ---------------- sims64 MFMA (bf16 inputs): 64 x 100000 x 768 in one vocab pass -----
__global__ __launch_bounds__(256) void sims64_mfma_kernel(
    const unsigned short* __restrict__ moA, const void* __restrict__ vocab,
    float* __restrict__ sims, float* __restrict__ invn,
    const int* __restrict__ dflag) {
    if (*dflag != 1) return;   // bf16 path only
    __shared__ unsigned short Bt[4096];   // [cc 0..7][row 0..63][e 0..7], 8 KB
    __shared__ float invLds[64];
    const unsigned short* voc = (const unsigned short*)vocab;
    int tid = threadIdx.x;
    int v0 = blockIdx.x * 64;
    int w = tid >> 6, lane = tid & 63;
    f32x4 acc[4];
    #pragma unroll
    for (int i = 0; i < 4; i++) acc[i] = (f32x4){0.f, 0.f, 0.f, 0.f};
    float ssqA = 0.f, ssqB = 0.f;
    int srow = tid >> 3;          // 0..31
    int scc  = tid & 7;           // 0..7
    for (int kb = 0; kb < 12; kb++) {
        #pragma unroll
        for (int q = 0; q < 2; q++) {
            int row = srow + q * 32;
            uint4 r = make_uint4(0u, 0u, 0u, 0u);
            if (v0 + row < NVOC)
                r = *(const uint4*)(voc + (size_t)(v0 + row) * 768 + kb * 64 + scc * 8);
            float s = 0.f;
            uint32_t us[4] = {r.x, r.y, r.z, r.w};
            #pragma unroll
            for (int t2 = 0; t2 < 4; t2++) {
                float f0 = __uint_as_float(us[t2] << 16);
                float f1 = __uint_as_float(us[t2] & 0xFFFF0000u);
                s += f0 * f0 + f1 * f1;
            }
            if (q == 0) ssqA += s; else ssqB += s;
            *(uint4*)&Bt[(scc * 64 + row) * 8] = r;
        }
        __syncthreads();
        #pragma unroll
        for (int ks = 0; ks < 2; ks++) {
            int kb2 = kb * 2 + ks;
            short8v ah = *(const short8v*)&moA[((((0 * 24 + kb2) * 4 + w) * 64) + lane) * 8];
            short8v al = *(const short8v*)&moA[((((1 * 24 + kb2) * 4 + w) * 64) + lane) * 8];
            int cc = ks * 4 + (lane >> 4);
            #pragma unroll
            for (int vs = 0; vs < 4; vs++) {
                int row = vs * 16 + (lane & 15);
                short8v bf = *(const short8v*)&Bt[(cc * 64 + row) * 8];
                acc[vs] = __builtin_amdgcn_mfma_f32_16x16x32_bf16(ah, bf, acc[vs], 0, 0, 0);
                acc[vs] = __builtin_amdgcn_mfma_f32_16x16x32_bf16(al, bf, acc[vs], 0, 0, 0);
            }
        }
        __syncthreads();
    }
    #pragma unroll
    for (int off = 1; off < 8; off <<= 1) {
        ssqA += __shfl_xor(ssqA, off, 64);
        ssqB += __shfl_xor(ssqB, off, 64);
    }
    if (scc == 0) {
        float iA = 1.0f / fmaxf(sqrtf(ssqA), 1e-12f);
        float iB = 1.0f / fmaxf(sqrtf(ssqB), 1e-12f);
        invLds[srow] = iA; invLds[srow + 32] = iB;
        if (v0 + srow < NVOC)      invn[v0 + srow] = iA;
        if (v0 + srow + 32 < NVOC) invn[v0 + srow + 32] = iB;
    }
    __syncthreads();
    #pragma unroll
    for (int vs = 0; vs < 4; vs++) {
        int v = v0 + vs * 16 + (lane & 15);
        if (v < NVOC) {
            float iv = invLds[vs * 16 + (lane & 15)];
            #pragma unroll
            for (int reg = 0; reg < 4; reg++) {
                int m = w * 16 + (lane >> 4) * 4 + reg;
                sims[(size_t)m * NVOC + v] = acc[vs][reg] * iv;
            }
        }
    }
}

// ---------------- sims64 MFMA (f32 inputs): hi/lo bf16 split both sides, 4 products --
// each product exact given hi/lo pairs; residual representation error ~2^-18/elem.
__global__ __launch_bounds__(256) void sims64_mfma_f32_kernel(
    const unsigned short* __restrict__ moA, const float* __restrict__ vocab,
    float* __restrict__ sims, float* __restrict__ invn,
    const int* __restrict__ dflag) {
    if (*dflag != 0) return;   // f32 path only
    __shared__ unsigned short Bh[4096];   // hi bf16, 8 KB
    __shared__ unsigned short Bl[4096];   // lo bf16, 8 KB
    __shared__ float invLds[64];
    int tid = threadIdx.x;
    int v0 = blockIdx.x * 64;
    int w = tid >> 6, lane = tid & 63;
    f32x4 acc[4];
    #pragma unroll
    for (int i = 0; i < 4; i++) acc[i] = (f32x4){0.f, 0.f, 0.f, 0.f};
    float ssqA = 0.f, ssqB = 0.f;
    int srow = tid >> 3;          // 0..31
    int scc  = tid & 7;           // 0..7
    for (int kb = 0; kb < 12; kb++) {
        #pragma unroll
        for (int q = 0; q < 2; q++) {
            int row = srow + q * 32;
            float4 xa = make_float4(0.f, 0.f, 0.f, 0.f);
            float4 xb = make_float4(0.f, 0.f, 0.f, 0.f);
            if (v0 + row < NVOC) {
                const float* s_ = vocab + (size_t)(v0 + row) * 768 + kb * 64 + scc * 8;
                xa = *(const float4*)s_;
                xb = *(const float4*)(s_ + 4);
            }
            float s = xa.x*xa.x + xa.y*xa.y + xa.z*xa.z + xa.w*xa.w
                    + xb.x*xb.x + xb.y*xb.y + xb.z*xb.z + xb.w*xb.w;
            if (q == 0) ssqA += s; else ssqB += s;
            float xv[8] = {xa.x, xa.y, xa.z, xa.w, xb.x, xb.y, xb.z, xb.w};
            uint32_t hw_[4], lw_[4];
            #pragma unroll
            for (int t = 0; t < 4; t++) {
                unsigned short h0 = f2bf(xv[2*t]),     h1 = f2bf(xv[2*t+1]);
                float l0 = xv[2*t] - b2f_raw(h0),      l1 = xv[2*t+1] - b2f_raw(h1);
                hw_[t] = (uint32_t)h0 | ((uint32_t)h1 << 16);
                lw_[t] = (uint32_t)f2bf(l0) | ((uint32_t)f2bf(l1) << 16);
            }
            *(uint4*)&Bh[(scc * 64 + row) * 8] = make_uint4(hw_[0], hw_[1], hw_[2], hw_[3]);
            *(uint4*)&Bl[(scc * 64 + row) * 8] = make_uint4(lw_[0], lw_[1], lw_[2], lw_[3]);
        }
        __syncthreads();
        #pragma unroll
        for (int ks = 0; ks < 2; ks++) {
            int kb2 = kb * 2 + ks;
            short8v ah = *(const short8v*)&moA[((((0 * 24 + kb2) * 4 + w) * 64) + lane) * 8];
            short8v al = *(const short8v*)&moA[((((1 * 24 + kb2) * 4 + w) * 64) + lane) * 8];
            int cc = ks * 4 + (lane >> 4);
            #pragma unroll
            for (int vs = 0; vs < 4; vs++) {
                int row = vs * 16 + (lane & 15);
                short8v bh = *(const short8v*)&Bh[(cc * 64 + row) * 8];
                short8v bl = *(const short8v*)&Bl[(cc * 64 + row) * 8];
                acc[vs] = __builtin_amdgcn_mfma_f32_16x16x32_bf16(ah, bh, acc[vs], 0, 0, 0);
                acc[vs] = __builtin_amdgcn_mfma_f32_16x16x32_bf16(al, bh, acc[vs], 0, 0, 0);
                acc[vs] = __builtin_amdgcn_mfma_f32_16x16x32_bf16(ah, bl, acc[vs], 0, 0, 0);
                acc[vs] = __builtin_amdgcn_mfma_f32_16x16x32_bf16(al, bl, acc[vs], 0, 0, 0);
            }
        }
        __syncthreads();
    }
    #pragma unroll
    for (int off = 1; off < 8; off <<= 1) {
        ssqA += __shfl_xor(ssqA, off, 64);
        ssqB += __shfl_xor(ssqB, off, 64);
    }
    if (scc == 0) {
        float iA = 1.0f / fmaxf(sqrtf(ssqA), 1e-12f);
        float iB = 1.0f / fmaxf(sqrtf(ssqB), 1e-12f);
        invLds[srow] = iA; invLds[srow + 32] = iB;
        if (v0 + srow < NVOC)      invn[v0 + srow] = iA;
        if (v0 + srow + 32 < NVOC) invn[v0 + srow + 32] = iB;
    }
    __syncthreads();
    #pragma unroll
    for (int vs = 0; vs < 4; vs++) {
        int v = v0 + vs * 16 + (lane & 15);
        if (v < NVOC) {
            float iv = invLds[vs * 16 + (lane & 15)];
            #pragma unroll
            for (int reg = 0; reg < 4; reg++) {
                int m = w * 16 + (lane >> 4) * 4 + reg;
                sims[(size_t)m * NVOC + v] = acc[vs][reg] * iv;
            }
        }
    }
}

// ---------------- sims (small-ws fallback 2-pass, 32 rows) ---------------------------
__global__ __launch_bounds__(256) void sims_kernel(
    const float* __restrict__ mo32, const void* __restrict__ vocab,
    float* __restrict__ sims, float* __restrict__ invn, int winv,
    const int* __restrict__ dflag) {
    __shared__ float xs[64][36];
    __shared__ float wt[64][68];
    int isbf = *dflag;
    int tid = threadIdx.x;
    int v0 = blockIdx.x * 64;
    int tx = tid & 15, ty = tid >> 4;
    float acc[2][4] = {{0.f}};
    float ssq[4] = {0.f, 0.f, 0.f, 0.f};
    for (int k0 = 0; k0 < 768; k0 += 64) {
        #pragma unroll
        for (int q = 0; q < 2; q++) {
            int e4 = tid + q * 256;
            int m = e4 >> 4, kk = (e4 & 15) * 4;
            float4 v = *(const float4*)(mo32 + (size_t)m * 768 + k0 + kk);
            xs[kk + 0][m] = v.x; xs[kk + 1][m] = v.y;
            xs[kk + 2][m] = v.z; xs[kk + 3][m] = v.w;
        }
        #pragma unroll
        for (int q = 0; q < 4; q++) {
            int e4 = tid + q * 256;
            int r = e4 >> 4, c = (e4 & 15) * 4;
            float4 v = make_float4(0.f, 0.f, 0.f, 0.f);
            if (v0 + r < NVOC)
                v = ldin4(vocab, (size_t)(v0 + r) * 768 + k0 + c, isbf);
            wt[c + 0][r] = v.x; wt[c + 1][r] = v.y;
            wt[c + 2][r] = v.z; wt[c + 3][r] = v.w;
        }
        __syncthreads();
        #pragma unroll 16
        for (int kk = 0; kk < 64; kk++) {
            float2 a = *(const float2*)&xs[kk][ty * 2];
            float4 w = *(const float4*)&wt[kk][tx * 4];
            ssq[0] += w.x * w.x; ssq[1] += w.y * w.y; ssq[2] += w.z * w.z; ssq[3] += w.w * w.w;
            acc[0][0] += a.x * w.x; acc[0][1] += a.x * w.y; acc[0][2] += a.x * w.z; acc[0][3] += a.x * w.w;
            acc[1][0] += a.y * w.x; acc[1][1] += a.y * w.y; acc[1][2] += a.y * w.z; acc[1][3] += a.y * w.w;
        }
        __syncthreads();
    }
    int v = v0 + tx * 4;
    if (v < NVOC) {
        float inv[4];
        #pragma unroll
        for (int j = 0; j < 4; j++) inv[j] = 1.0f / fmaxf(sqrtf(ssq[j]), 1e-12f);
        #pragma unroll
        for (int i = 0; i < 2; i++) {
            float4 o = make_float4(acc[i][0] * inv[0], acc[i][1] * inv[1],
                                   acc[i][2] * inv[2], acc[i][3] * inv[3]);
            *(float4*)(sims + (size_t)(ty * 2 + i) * NVOC + v) = o;
        }
        if (ty == 0 && winv) *(float4*)(invn + v) = make_float4(inv[0], inv[1], inv[2], inv[3]);
    }
}

// ---------------- bitonic sort desc on u64 keys ----------------
__device__ void bitonic_desc_u64(unsigned long long* d, int n, int tid, int nt) {
    for (int k = 2; k <= n; k <<= 1) {
        for (int j = k >> 1; j > 0; j >>= 1) {
            for (int i = tid; i < n; i += nt) {
                int ixj = i ^ j;
                if (ixj > i) {
                    unsigned long long a = d[i], b = d[ixj];
                    bool up = ((i & k) == 0);
                    if (up ? (a < b) : (a > b)) { d[i] = b; d[ixj] = a; }
                }
            }
            __syncthreads();
        }
    }
}

// ---------------- partitioned exact top-512 (jax.lax.top_k semantics) ----------------
__global__ __launch_bounds__(1024) void pselect_kernel(
    const float* __restrict__ sims, unsigned long long* __restrict__ psel) {
    __shared__ int hist[4096];
    __shared__ unsigned long long cand[2048];
    __shared__ int ssum[1024];
    __shared__ int s_Tg, s_T, s_cnt;
    int b = blockIdx.y, part = blockIdx.x, tid = threadIdx.x;
    const float* row = sims + (size_t)b * NVOC + (size_t)part * PLEN;
    #pragma unroll
    for (int q = 0; q < 4; q++) hist[tid * 4 + q] = 0;
    __syncthreads();
    for (int v = tid; v < PLEN; v += 1024) {
        uint32_t u = fmono(row[v]);
        atomicAdd(&hist[u >> 20], 1);
    }
    __syncthreads();
    int a_ = 0;
    #pragma unroll
    for (int q = 0; q < 4; q++) a_ += hist[tid * 4 + q];
    ssum[tid] = a_; __syncthreads();
    for (int off = 1; off < 1024; off <<= 1) {
        int add = (tid + off < 1024) ? ssum[tid + off] : 0;
        __syncthreads();
        ssum[tid] += add;
        __syncthreads();
    }
    if (ssum[tid] >= VK && (tid == 1023 || ssum[tid + 1] < VK)) s_Tg = tid;
    __syncthreads();
    if (tid == 0) {
        int g = s_Tg;
        int above = (g == 1023) ? 0 : ssum[g + 1];
        int T = g * 4;
        for (int bin = g * 4 + 3; bin >= g * 4; bin--) {
            int c = hist[bin];
            if (above + c >= VK) { T = bin; break; }
            above += c;
        }
        s_T = T; s_cnt = 0;
    }
    __syncthreads();
    uint32_t T = (uint32_t)s_T;
    for (int v = tid; v < PLEN; v += 1024) {
        uint32_t u = fmono(row[v]);
        if ((u >> 20) >= T) {
            int p = atomicAdd(&s_cnt, 1);
            if (p < 2048) {
                uint32_t vg = (uint32_t)(part * PLEN + v);
                cand[p] = ((unsigned long long)u << 32) | (uint32_t)(~vg);
            }
        }
    }
    __syncthreads();
    int total = min(s_cnt, 2048);
    for (int i = tid; i < 2048; i += 1024)
        if (i >= total) cand[i] = 0ull;
    __syncthreads();
    bitonic_desc_u64(cand, 2048, tid, 1024);
    if (tid < VK) psel[((size_t)b * NPART + part) * VK + tid] = cand[tid];
}

__global__ __launch_bounds__(512) void pmerge_kernel(
    const unsigned long long* __restrict__ psel, int* __restrict__ top_idx) {
    __shared__ unsigned long long key[2048];
    int b = blockIdx.x, tid = threadIdx.x;
    for (int i = tid; i < 2048; i += 512) key[i] = psel[(size_t)b * 2048 + i];
    __syncthreads();
    bitonic_desc_u64(key, 2048, tid, 512);
    if (tid < VK) top_idx[(size_t)b * VK + tid] = (int)(~(uint32_t)(key[tid] & 0xFFFFFFFFull));
}

// ---------------- small-ws fallback: full-row top-512 ----------------
__global__ __launch_bounds__(1024) void select512_kernel(
    const float* __restrict__ sims, int* __restrict__ top_idx) {
    __shared__ int hist[4096];
    __shared__ unsigned long long cand[4096];
    __shared__ int ssum[1024];
    __shared__ int s_Tg, s_T, s_cnt;
    int b = blockIdx.x, tid = threadIdx.x;
    const float* row = sims + (size_t)b * NVOC;
    #pragma unroll
    for (int q = 0; q < 4; q++) hist[tid * 4 + q] = 0;
    __syncthreads();
    for (int v = tid; v < NVOC; v += 1024) {
        uint32_t u = fmono(row[v]);
        atomicAdd(&hist[u >> 20], 1);
    }
    __syncthreads();
    int a_ = 0;
    #pragma unroll
    for (int q = 0; q < 4; q++) a_ += hist[tid * 4 + q];
    ssum[tid] = a_; __syncthreads();
    for (int off = 1; off < 1024; off <<= 1) {
        int add = (tid + off < 1024) ? ssum[tid + off] : 0;
        __syncthreads();
        ssum[tid] += add;
        __syncthreads();
    }
    if (ssum[tid] >= VK && (tid == 1023 || ssum[tid + 1] < VK)) s_Tg = tid;
    __syncthreads();
    if (tid == 0) {
        int g = s_Tg;
        int above = (g == 1023) ? 0 : ssum[g + 1];
        int T = g * 4;
        for (int bin = g * 4 + 3; bin >= g * 4; bin--) {
            int c = hist[bin];
            if (above + c >= VK) { T = bin; break; }
            above += c;
        }
        s_T = T; s_cnt = 0;
    }
    __syncthreads();
    uint32_t T = (uint32_t)s_T;
    for (int v = tid; v < NVOC; v += 1024) {
        uint32_t u = fmono(row[v]);
        if ((u >> 20) >= T) {
            int p = atomicAdd(&s_cnt, 1);
            if (p < 4096) cand[p] = ((unsigned long long)u << 32) | (uint32_t)(~v);
        }
    }
    __syncthreads();
    int total = min(s_cnt, 4096);
    for (int i = tid; i < 4096; i += 1024)
        if (i >= total) cand[i] = 0ull;
    __syncthreads();
    bitonic_desc_u64(cand, 4096, tid, 1024);
    if (tid < VK) top_idx[(size_t)b * VK + tid] = (int)(~(uint32_t)(cand[tid] & 0xFFFFFFFFull));
}

// ---------------- per-candidate 25 sims -> primary/secondary -> tot_reward ------------
__global__ __launch_bounds__(128) void tot_kernel(
    const int* __restrict__ top_idx, const void* __restrict__ vocab,
    const float* __restrict__ invn, const float* __restrict__ invemb,
    const void* __restrict__ pos, const void* __restrict__ neg,
    const void* __restrict__ neut, const void* __restrict__ assas,
    float* __restrict__ tot, const int* __restrict__ dflag) {
    __shared__ float E[25 * 384];
    int isbf = *dflag;
    int b = blockIdx.y;
    int j = blockIdx.x * 128 + threadIdx.x;
    int v = top_idx[(size_t)b * VK + j];
    if ((unsigned)v >= (unsigned)NVOC) v = 0;
    size_t vbase = (size_t)v * D_;
    float p[25];
    #pragma unroll
    for (int i = 0; i < 25; i++) p[i] = 0.f;

    for (int h = 0; h < 2; h++) {
        __syncthreads();
        for (int u = threadIdx.x; u < 2400; u += 128) {
            int i = u / 96;
            int c = (u - i * 96) * 4;
            const void* ep; size_t eb;
            if (i < 9)       { ep = pos;   eb = ((size_t)b * 9 + i) * D_; }
            else if (i < 17) { ep = neg;   eb = ((size_t)b * 8 + (i - 9)) * D_; }
            else if (i < 24) { ep = neut;  eb = ((size_t)b * 7 + (i - 17)) * D_; }
            else             { ep = assas; eb = (size_t)b * D_; }
            float4 x = ldin4(ep, eb + h * 384 + c, isbf);
            float s = invemb[b * 25 + i];
            E[i * 384 + c + 0] = x.x * s;
            E[i * 384 + c + 1] = x.y * s;
            E[i * 384 + c + 2] = x.z * s;
            E[i * 384 + c + 3] = x.w * s;
        }
        __syncthreads();
        for (int c = 0; c < 384; c += 4) {
            float4 w = ldin4(vocab, vbase + h * 384 + c, isbf);
            #pragma unroll
            for (int i = 0; i < 25; i++) {
                float4 e = *(const float4*)&E[i * 384 + c];
                p[i] += w.x * e.x + w.y * e.y + w.z * e.z + w.w * e.w;
            }
        }
    }

    float invv = invn[v];
    #pragma unroll
    for (int i = 0; i < 25; i++) p[i] *= invv;
    float mx = -1e30f; int am = 9;
    #pragma unroll
    for (int i = 9; i < 25; i++) if (p[i] > mx) { mx = p[i]; am = i; }
    int primary = 0;
    #pragma unroll
    for (int i = 0; i < 9; i++) primary += (p[i] >= mx) ? 1 : 0;
    float secondary = (am == 24) ? -10.0f : ((am >= 17) ? 1.0f : 0.0f);
    tot[(size_t)b * VK + j] = (float)primary + secondary;
}

// ---------------- top/bottom 256 of tot (exact tie semantics) ----------------
__global__ __launch_bounds__(256) void sort512_kernel(
    const float* __restrict__ tot, int* __restrict__ idx_max, int* __restrict__ idx_min) {
    __shared__ unsigned long long key[512];
    int b = blockIdx.x, tid = threadIdx.x;
    for (int pass = 0; pass < 2; pass++) {
        for (int j = tid; j < 512; j += 256) {
            uint32_t m = fmono(tot[(size_t)b * VK + j]);
            if (pass) m = ~m;
            key[j] = ((unsigned long long)m << 32) | (uint32_t)(511 - j);
        }
        __syncthreads();
        bitonic_desc_u64(key, 512, tid, 256);
        int* dst = pass ? idx_min : idx_max;
        if (tid < 256) dst[(size_t)b * KH + tid] = 511 - (int)(key[tid] & 0xFFFFFFFFull);
        __syncthreads();
    }
}

// ---------------- gather + mean + normalize; search_embedding bit-exact copy ----------
__global__ __launch_bounds__(256) void pool_kernel(
    const int* __restrict__ top_idx, const int* __restrict__ idx_max,
    const int* __restrict__ idx_min, const void* __restrict__ vocab,
    float* __restrict__ out, const int* __restrict__ dflag) {
    __shared__ float red[256];
    int isbf = *dflag;
    int b = blockIdx.x, s = blockIdx.y, tid = threadIdx.x;
    const int* sel = s ? idx_min : idx_max;
    int d = tid * 3;
    float a0 = 0.f, a1 = 0.f, a2 = 0.f;
    for (int r = 0; r < 256; r++) {
        int v = top_idx[(size_t)b * VK + sel[(size_t)b * KH + r]];
        if ((unsigned)v >= (unsigned)NVOC) v = 0;
        size_t vb = (size_t)v * D_ + d;
        a0 += ldin(vocab, vb + 0, isbf);
        a1 += ldin(vocab, vb + 1, isbf);
        a2 += ldin(vocab, vb + 2, isbf);
    }
    a0 *= (1.0f / 256.0f); a1 *= (1.0f / 256.0f); a2 *= (1.0f / 256.0f);
    float S = block_reduce_sum_256(a0 * a0 + a1 * a1 + a2 * a2, red);
    float inv = 1.0f / fmaxf(sqrtf(S), 1e-12f);
    float* o = out + (size_t)(2 + s) * (B_ * D_) + (size_t)b * D_ + d;
    o[0] = a0 * inv;
    o[1] = a1 * inv;
    o[2] = a2 * inv;
    if (s == 0) {
        int v0 = top_idx[(size_t)b * VK + sel[(size_t)b * KH + 0]];
        if ((unsigned)v0 >= (unsigned)NVOC) v0 = 0;
        size_t vb = (size_t)v0 * D_ + d;
        float* so = out + (size_t)(B_ * D_) + (size_t)b * D_ + d;
        so[0] = ldin(vocab, vb + 0, isbf);
        so[1] = ldin(vocab, vb + 1, isbf);
        so[2] = ldin(vocab, vb + 2, isbf);
    }
}

extern "C" void kernel_launch(void* const* d_in, const int* in_sizes, int n_in,
                              void* d_out, int out_size, void* d_ws, size_t ws_size,
                              hipStream_t stream) {
    const void* pos   = d_in[0];
    const void* neg   = d_in[1];
    const void* neut  = d_in[2];
    const void* assas = d_in[3];
    const void* vocab = d_in[4];
    const void* W1 = d_in[5];  const void* b1 = d_in[6];
    const void* W2 = d_in[7];  const void* b2 = d_in[8];
    const void* W3 = d_in[9];  const void* b3 = d_in[10];
    const void* W4 = d_in[11]; const void* b4 = d_in[12];
    float* out = (float*)d_out;

    int big = ws_size >= (size_t)32 * 1024 * 1024;

    float* ws = (float*)d_ws;
    if (big) {
        float* concat = ws;                              // 196608
        float* h1     = concat + 196608;                 // 147456
        float* h2     = h1 + 147456;                     // 108800
        float* h3     = h2 + 108800;                     //  64000
        float* mo     = h3 + 64000;                      //  49152
        float* moT    = mo + 49152;                      //  49152
        float* moA_f  = moT + 49152;                     //  49152 (98304 bf16)
        float* invn   = moA_f + 49152;                   // 100000
        float* invemb = invn + 100000;                   //   1600
        float* simsPb = invemb + 1600;                   // 6400000
        int* top_idx  = (int*)(simsPb + 6400000);        // 32768
        float* tot    = (float*)(top_idx + 64 * VK);     // 32768
        int* imax     = (int*)(tot + 64 * VK);           // 16384
        int* imin     = imax + 64 * KH;                  // 16384
        unsigned long long* psel = (unsigned long long*)(imin + 64 * KH); // 131072 u64
        int* dflag    = (int*)(psel + 64 * NPART * VK);  // 1
        unsigned short* moAu = (unsigned short*)moA_f;

        detect_kernel<<<1, 64, 0, stream>>>(vocab, dflag);
        prep_kernel<<<64, 256, 0, stream>>>(pos, neg, neut, assas, concat, invemb, dflag);

        gemm_partial_kernel<<<dim3(36, 8), 256, 0, stream>>>(concat, W1, simsPb, 3072, 2304, 384, dflag);
        reduce_act_kernel<<<576, 256, 0, stream>>>(simsPb, b1, h1, 2304, 8, 1, dflag);
        gemm_partial_kernel<<<dim3(27, 9), 256, 0, stream>>>(h1, W2, simsPb, 2304, 1700, 256, dflag);
        reduce_act_kernel<<<425, 256, 0, stream>>>(simsPb, b2, h2, 1700, 9, 1, dflag);
        gemm_partial_kernel<<<dim3(16, 9), 256, 0, stream>>>(h2, W3, simsPb, 1700, 1000, 192, dflag);
        reduce_act_kernel<<<250, 256, 0, stream>>>(simsPb, b3, h3, 1000, 9, 1, dflag);
        gemm_partial_kernel<<<dim3(12, 8), 256, 0, stream>>>(h3, W4, simsPb, 1000, 768, 128, dflag);
        reduce_act_kernel<<<192, 256, 0, stream>>>(simsPb, b4, mo, 768, 8, 0, dflag);

        norm_mo_kernel<<<64, 256, 0, stream>>>(mo, out, moT, moAu);

        // dtype-gated MFMA pair: exactly one does the work, the other retires immediately
        sims64_mfma_kernel<<<1563, 256, 0, stream>>>(moAu, vocab, simsPb, invn, dflag);
        sims64_mfma_f32_kernel<<<1563, 256, 0, stream>>>(moAu, (const float*)vocab,
                                                         simsPb, invn, dflag);

        pselect_kernel<<<dim3(NPART, 64), 1024, 0, stream>>>(simsPb, psel);
        pmerge_kernel<<<64, 512, 0, stream>>>(psel, top_idx);

        tot_kernel<<<dim3(4, 64), 128, 0, stream>>>(top_idx, vocab, invn, invemb,
                                                    pos, neg, neut, assas, tot, dflag);
        sort512_kernel<<<64, 256, 0, stream>>>(tot, imax, imin);
        pool_kernel<<<dim3(64, 2), 256, 0, stream>>>(top_idx, imax, imin, vocab, out, dflag);
    } else {
        float* concat = ws;                              // 196608
        float* h1     = concat + 196608;                 // 147456
        float* h2     = h1 + 147456;                     // 108800
        float* h3     = h2 + 108800;                     //  64000
        float* mo     = h3 + 64000;                      //  49152
        float* invn   = mo + 49152;                      // 100000
        float* invemb = invn + 100000;                   //   1600
        float* simsPb = invemb + 1600;                   // 3200000
        int* top_idx  = (int*)(simsPb + 3200000);        // 32768
        float* tot    = (float*)(top_idx + 64 * VK);     // 32768
        int* imax     = (int*)(tot + 64 * VK);           // 16384
        int* imin     = imax + 64 * KH;                  // 16384
        int* dflag    = imin + 64 * KH;                  // 1

        detect_kernel<<<1, 64, 0, stream>>>(vocab, dflag);
        prep_kernel<<<64, 256, 0, stream>>>(pos, neg, neut, assas, concat, invemb, dflag);

        gemm_partial_kernel<<<dim3(36, 8), 256, 0, stream>>>(concat, W1, simsPb, 3072, 2304, 384, dflag);
        reduce_act_kernel<<<576, 256, 0, stream>>>(simsPb, b1, h1, 2304, 8, 1, dflag);
        gemm_partial_kernel<<<dim3(27, 9), 256, 0, stream>>>(h1, W2, simsPb, 2304, 1700, 256, dflag);
        reduce_act_kernel<<<425, 256, 0, stream>>>(simsPb, b2, h2, 1700, 9, 1, dflag);
        gemm_partial_kernel<<<dim3(16, 9), 256, 0, stream>>>(h2, W3, simsPb, 1700, 1000, 192, dflag);
        reduce_act_kernel<<<250, 256, 0, stream>>>(simsPb, b3, h3, 1000, 9, 1, dflag);
        gemm_partial_kernel<<<dim3(12, 8), 256, 0, stream>>>(h3, W4, simsPb, 1000, 768, 128, dflag);
        reduce_act_kernel<<<192, 256, 0, stream>>>(simsPb, b4, mo, 768, 8, 0, dflag);

        norm_mo_kernel<<<64, 256, 0, stream>>>(mo, out, nullptr, nullptr);

        for (int pass = 0; pass < 2; pass++) {
            sims_kernel<<<1563, 256, 0, stream>>>(mo + (size_t)pass * 32 * D_, vocab,
                                                  simsPb, invn, pass == 0, dflag);
            select512_kernel<<<32, 1024, 0, stream>>>(simsPb, top_idx + (size_t)pass * 32 * VK);
        }

        tot_kernel<<<dim3(4, 64), 128, 0, stream>>>(top_idx, vocab, invn, invemb,
                                                    pos, neg, neut, assas, tot, dflag);
        sort512_kernel<<<64, 256, 0, stream>>>(tot, imax, imin);
        pool_kernel<<<dim3(64, 2), 256, 0, stream>>>(top_idx, imax, imin, vocab, out, dflag);
    }
}